// Round 14
// baseline (362.092 us; speedup 1.0000x reference)
//
#include <hip/hip_runtime.h>
#include <hip/hip_bf16.h>
#include <math.h>

#define H 16
#define KVH 4
#define D 128
#define HID 2048
#define TOPK 128
#define NQKV 5120   // 2048 q + 512 k + 512 v + 2048 q2
#define SCALE 0.088388347648318447f
#define KCH 384     // PV K-split chunk

typedef __attribute__((ext_vector_type(8))) short bf16x8;
typedef __attribute__((ext_vector_type(4))) float f32x4;
typedef unsigned short u16;

__device__ __forceinline__ float bf2f(u16 u) {
    return __uint_as_float(((unsigned)u) << 16);
}
__device__ __forceinline__ u16 f2bf(float f) {
    unsigned x = __float_as_uint(f);
    x += 0x7fffu + ((x >> 16) & 1u);   // RNE
    return (u16)(x >> 16);
}
__device__ __forceinline__ unsigned pk2(float a, float b, float sc) {
    return (unsigned)f2bf(a * sc) | ((unsigned)f2bf(b * sc) << 16);
}

__device__ __forceinline__ float wave_red_sum(float v) {
#pragma unroll
    for (int o = 32; o > 0; o >>= 1) v += __shfl_xor(v, o, 64);
    return v;
}
__device__ __forceinline__ float block_red_sum(float v, float* sb) {
    v = wave_red_sum(v);
    int w = threadIdx.x >> 6;
    if ((threadIdx.x & 63) == 0) sb[w] = v;
    __syncthreads();
    float r = (sb[0] + sb[1]) + (sb[2] + sb[3]);
    __syncthreads();
    return r;
}

#define GLOAD16(g, l) __builtin_amdgcn_global_load_lds( \
    (const __attribute__((address_space(1))) void*)(g), \
    (__attribute__((address_space(3))) void*)(l), 16, 0, 0)

// convert one 256th of a HID*HID f32 weight to bf16 (16 f32x4 / thread)
__device__ __forceinline__ void conv_w_block(const float* __restrict__ src,
        u16* __restrict__ dst, int cidx) {
    const f32x4* p = (const f32x4*)src;
    uint2* o = (uint2*)dst;
    long base = (long)cidx * 4096;
#pragma unroll
    for (int it = 0; it < 16; ++it) {
        long i = base + it * 256 + threadIdx.x;
        f32x4 v = __builtin_nontemporal_load(p + i);
        o[i] = make_uint2(pk2(v.x, v.y, 1.f), pk2(v.z, v.w, 1.f));
    }
}

// ---------------- shared MFMA core: 128x128 C-tile, BK=64, 4 waves ----------------
__device__ __forceinline__ void mfma_core_128(
    const u16* A, int lda, const u16* B, int ldb, int K,
    u16* As, u16* Bs, int m0, int n0, f32x4 (&acc)[4][4])
{
    const int tid = threadIdx.x;
    const int lane = tid & 63, wid = tid >> 6;
    const int wr = (wid >> 1) * 64, wc = (wid & 1) * 64;
    const int fr = lane & 15, kg = lane >> 4;

    const u16* ga[4]; const u16* gb[4];
#pragma unroll
    for (int i = 0; i < 4; ++i) {
        int c = tid + i * 256;
        int row = c >> 3;
        int col8 = (c & 7) ^ (row & 7);
        ga[i] = A + (size_t)(m0 + row) * lda + col8 * 8;
        gb[i] = B + (size_t)(n0 + row) * ldb + col8 * 8;
    }
    const int xorm = (fr & 7) << 4;
    const int sA0 = ((wr + fr) * 128 + (((kg * 16)     ) ^ xorm)) >> 1;
    const int sA1 = ((wr + fr) * 128 + (((kg * 16) + 64) ^ xorm)) >> 1;
    const int sB0 = ((wc + fr) * 128 + (((kg * 16)     ) ^ xorm)) >> 1;
    const int sB1 = ((wc + fr) * 128 + (((kg * 16) + 64) ^ xorm)) >> 1;

    for (int k0 = 0; k0 < K; k0 += 64) {
#pragma unroll
        for (int i = 0; i < 4; ++i) {
            GLOAD16(ga[i], As + (size_t)wid * 512 + i * 2048);  // +lane*16B implicit
            GLOAD16(gb[i], Bs + (size_t)wid * 512 + i * 2048);
            ga[i] += 64; gb[i] += 64;
        }
        __syncthreads();
#pragma unroll
        for (int s = 0; s < 2; ++s) {
            const int oA = s ? sA1 : sA0;
            const int oB = s ? sB1 : sB0;
            bf16x8 af[4], bg[4];
#pragma unroll
            for (int i = 0; i < 4; ++i) af[i] = *(const bf16x8*)(As + oA + i * 1024);
#pragma unroll
            for (int j = 0; j < 4; ++j) bg[j] = *(const bf16x8*)(Bs + oB + j * 1024);
#pragma unroll
            for (int i = 0; i < 4; ++i)
#pragma unroll
                for (int j = 0; j < 4; ++j)
                    acc[i][j] = __builtin_amdgcn_mfma_f32_16x16x32_bf16(af[i], bg[j], acc[i][j], 0, 0, 0);
        }
        __syncthreads();
    }
}

__device__ __forceinline__ void gemm_epilogue_bf16(
    f32x4 (&acc)[4][4], const float* bias, u16* C, int ldc, int m0, int n0)
{
    const int tid = threadIdx.x, lane = tid & 63, wid = tid >> 6;
    const int wr = (wid >> 1) * 64, wc = (wid & 1) * 64;
    const int fr = lane & 15, kg = lane >> 4;
#pragma unroll
    for (int i = 0; i < 4; ++i) {
        int r0 = m0 + wr + i * 16 + kg * 4;
#pragma unroll
        for (int j = 0; j < 4; ++j) {
            int c = n0 + wc + j * 16 + fr;
            float bb = bias ? bias[c] : 0.0f;
#pragma unroll
            for (int r = 0; r < 4; ++r)
                C[(size_t)(r0 + r) * ldc + c] = f2bf(acc[i][j][r] + bb);
        }
    }
}

// ---------------- MERGED: QKV proj + KB-stats GEMM (+appended Wvn conversion) ----------------
__global__ __launch_bounds__(256, 3) void gemm_proj_all(
    const u16* __restrict__ hsbf, const u16* __restrict__ wpack,
    const float* __restrict__ bpk, u16* __restrict__ qkv,
    const u16* __restrict__ kebf, const u16* __restrict__ wknbf,
    const float* __restrict__ bkn,
    float* __restrict__ part_s, float* __restrict__ part_ss, int S, int KB,
    const float* __restrict__ Wvn, u16* __restrict__ wvnbf)
{
    __shared__ u16 As[8192], Bs[8192];
    __shared__ float sred[2][128], ssred[2][128];
    const int nqkvb = (NQKV / 128) * (S / 128);
    const int ntot = nqkvb + (HID / 128) * (KB / 128);
    int b = blockIdx.x;
    if (b >= ntot) {              // appended blocks: convert Wvn (overlaps GEMM)
        conv_w_block(Wvn, wvnbf, b - ntot);
        return;
    }
    if ((ntot & 7) == 0) { int cpx = ntot >> 3; b = (b & 7) * cpx + (b >> 3); }
    f32x4 acc[4][4] = {};
    const int tid = threadIdx.x, lane = tid & 63, wid = tid >> 6;
    const int wr = (wid >> 1) * 64, wc = (wid & 1) * 64;
    const int fr = lane & 15, kg = lane >> 4;
    if (b < nqkvb) {
        int bx = b % (NQKV / 128), by = b / (NQKV / 128);
        int m0 = by * 128, n0 = bx * 128;
        mfma_core_128(hsbf, HID, wpack, HID, HID, As, Bs, m0, n0, acc);
        gemm_epilogue_bf16(acc, bpk, qkv, NQKV, m0, n0);
    } else {
        int b2 = b - nqkvb;
        int bx = b2 & 15, by = b2 >> 4;
        int m0 = by * 128, n0 = bx * 128;
        mfma_core_128(kebf, HID, wknbf, HID, HID, As, Bs, m0, n0, acc);
#pragma unroll
        for (int i = 0; i < 4; ++i) {
            float rs[4] = {0.f, 0.f, 0.f, 0.f}, rss[4] = {0.f, 0.f, 0.f, 0.f};
#pragma unroll
            for (int j = 0; j < 4; ++j) {
                float bb = bkn[n0 + wc + j * 16 + fr];
#pragma unroll
                for (int r = 0; r < 4; ++r) {
                    float v = acc[i][j][r] + bb;
                    rs[r] += v; rss[r] += v * v;
                }
            }
#pragma unroll
            for (int o = 1; o < 16; o <<= 1) {
#pragma unroll
                for (int r = 0; r < 4; ++r) {
                    rs[r]  += __shfl_xor(rs[r],  o, 64);
                    rss[r] += __shfl_xor(rss[r], o, 64);
                }
            }
            if (fr == 0) {
#pragma unroll
                for (int r = 0; r < 4; ++r) {
                    sred[wid & 1][wr + i * 16 + kg * 4 + r]  = rs[r];
                    ssred[wid & 1][wr + i * 16 + kg * 4 + r] = rss[r];
                }
            }
        }
        __syncthreads();
        if (tid < 128) {
            part_s[(size_t)bx * KB + m0 + tid]  = sred[0][tid] + sred[1][tid];
            part_ss[(size_t)bx * KB + m0 + tid] = ssred[0][tid] + ssred[1][tid];
        }
    }
}

// ---------------- selected-row pair GEMM (bf16): z=0 kbk(LN), z=1 kbv ----------------
__global__ __launch_bounds__(256, 3) void gemm_sel_pair(
    const u16* __restrict__ ksel, const u16* __restrict__ vsel,
    const u16* __restrict__ Bk, const u16* __restrict__ Bv,
    const float* __restrict__ bkn, const float* __restrict__ bvn,
    const float* __restrict__ mu, const float* __restrict__ inv,
    const int* __restrict__ idx, u16* __restrict__ Ck, u16* __restrict__ Cv)
{
    __shared__ u16 As[8192], Bs[8192];
    const int z = blockIdx.z;
    const u16* A = z ? vsel : ksel;
    const u16* B = z ? Bv : Bk;
    const float* bias = z ? bvn : bkn;
    u16* C = z ? Cv : Ck;
    const int n0 = blockIdx.x * 128;
    f32x4 acc[4][4] = {};
    mfma_core_128(A, HID, B, HID, HID, As, Bs, 0, n0, acc);
    const int tid = threadIdx.x, lane = tid & 63, wid = tid >> 6;
    const int wr = (wid >> 1) * 64, wc = (wid & 1) * 64;
    const int fr = lane & 15, kg = lane >> 4;
#pragma unroll
    for (int i = 0; i < 4; ++i) {
        int r0 = wr + i * 16 + kg * 4;
#pragma unroll
        for (int j = 0; j < 4; ++j) {
            int c = n0 + wc + j * 16 + fr;
            float bb = bias[c];
#pragma unroll
            for (int r = 0; r < 4; ++r) {
                float v = acc[i][j][r] + bb;
                if (z == 0) {
                    int g = idx[r0 + r];
                    v = (v - mu[g]) * inv[g];
                }
                C[(size_t)(r0 + r) * HID + c] = f2bf(v);
            }
        }
    }
}

// ---------------- MERGED logits + per-tile row max (+appended Wo conversion) ----------------
__global__ __launch_bounds__(256, 3) void logits_all(
    const u16* __restrict__ qkv, const u16* __restrict__ kbksel,
    u16* __restrict__ logits, float* __restrict__ rmaxpart, int S,
    const float* __restrict__ Wo, u16* __restrict__ wobf)
{
    __shared__ u16 As[8192], Bs[8192];
    __shared__ float rex[2][128];
    const int h = blockIdx.y;
    const int NS = S >> 7;
    const int npairs = NS * (NS + 1) / 2;
    const int gbase = npairs + NS;
    const int LT = TOPK + S;
    int x = blockIdx.x;
    if (x >= gbase) {             // appended blocks: convert Wo (overlaps GEMM)
        conv_w_block(Wo, wobf, (x - gbase) + 16 * h);
        return;
    }
    f32x4 acc[4][4] = {};
    const int tid = threadIdx.x, lane = tid & 63, wid = tid >> 6;
    const int wr = (wid >> 1) * 64, wc = (wid & 1) * 64;
    const int fr = lane & 15, kg = lane >> 4;
    float pmax[4][4];
#pragma unroll
    for (int i = 0; i < 4; ++i)
#pragma unroll
        for (int r = 0; r < 4; ++r) pmax[i][r] = -3.0e38f;
    int rowbase, tslot;
    if (x < npairs) {
        int s0t = 0;
        while ((s0t + 1) * (s0t + 2) / 2 <= x) ++s0t;
        int j0t = x - s0t * (s0t + 1) / 2;
        int s0 = s0t * 128, j0 = j0t * 128;
        mfma_core_128(qkv + h * D, NQKV, qkv + HID + (h >> 2) * D, NQKV, D,
                      As, Bs, s0, j0, acc);
#pragma unroll
        for (int i = 0; i < 4; ++i) {
            int r0 = s0 + wr + i * 16 + kg * 4;
#pragma unroll
            for (int j = 0; j < 4; ++j) {
                int c = j0 + wc + j * 16 + fr;
#pragma unroll
                for (int r = 0; r < 4; ++r) {
                    float v = (c <= r0 + r) ? acc[i][j][r] : -1.0e30f;
                    pmax[i][r] = fmaxf(pmax[i][r], v);
                    logits[((size_t)h * S + r0 + r) * LT + TOPK + c] = f2bf(v);
                }
            }
        }
        rowbase = s0; tslot = j0t + 1;
    } else {
        int m0 = (x - npairs) * 128;
        mfma_core_128(qkv + 3072 + h * D, NQKV, kbksel + h * D, HID, D,
                      As, Bs, m0, 0, acc);
#pragma unroll
        for (int i = 0; i < 4; ++i) {
            int r0 = m0 + wr + i * 16 + kg * 4;
#pragma unroll
            for (int j = 0; j < 4; ++j) {
                int c = wc + j * 16 + fr;
#pragma unroll
                for (int r = 0; r < 4; ++r) {
                    float v = acc[i][j][r];
                    pmax[i][r] = fmaxf(pmax[i][r], v);
                    logits[((size_t)h * S + r0 + r) * LT + c] = f2bf(v);
                }
            }
        }
        rowbase = m0; tslot = 0;
    }
#pragma unroll
    for (int o = 1; o < 16; o <<= 1)
#pragma unroll
        for (int i = 0; i < 4; ++i)
#pragma unroll
            for (int r = 0; r < 4; ++r)
                pmax[i][r] = fmaxf(pmax[i][r], __shfl_xor(pmax[i][r], o, 64));
    __syncthreads();
    if (fr == 0) {
#pragma unroll
        for (int i = 0; i < 4; ++i)
#pragma unroll
            for (int r = 0; r < 4; ++r)
                rex[wid & 1][wr + i * 16 + kg * 4 + r] = pmax[i][r];
    }
    __syncthreads();
    if (tid < 128)
        rmaxpart[((size_t)h * S + rowbase + tid) * 10 + tslot] =
            fmaxf(rex[0][tid], rex[1][tid]);
}

// ---------------- PV K-split with inline exp (+inline rmax combine) ----------------
__global__ __launch_bounds__(256, 3) void pv_exp_split(
    const u16* __restrict__ logits, const u16* __restrict__ valsT,
    const float* __restrict__ rmaxpart, u16* __restrict__ attp,
    float* __restrict__ rowsump, int S)
{
    const int m0 = blockIdx.x * 128, h = blockIdx.y, c = blockIdx.z;
    const int LT = TOPK + S;
    const int Klim = TOPK + m0 + 128;
    const int kbeg = c * KCH;
    if (kbeg >= Klim) return;
    const int K = min(KCH, Klim - kbeg);
    __shared__ u16 As[8192], Bs[8192];
    __shared__ float rowsum[128];
    __shared__ float rowmax[128];
    const int tid = threadIdx.x, lane = tid & 63, wid = tid >> 6;
    const int wr = (wid >> 1) * 64, wc = (wid & 1) * 64;
    const int fr = lane & 15, kg = lane >> 4;
    const int srow = tid >> 3, scol8 = tid & 7;
    if (tid < 128) {
        rowsum[tid] = 0.f;
        int s = m0 + tid;
        int ntt = (s >> 7) + 2;
        const float* rp = rmaxpart + ((size_t)h * S + s) * 10;
        float m = -3.0e38f;
        for (int t = 0; t < ntt; ++t) m = fmaxf(m, rp[t]);
        rowmax[tid] = m;
    }
    int woff[4];
#pragma unroll
    for (int j = 0; j < 4; ++j) {
        int row = srow + j * 32;
        woff[j] = (row * 128 + ((scol8 * 16) ^ ((row & 7) * 16))) >> 1;
    }
    __syncthreads();
    float rmx[4];
#pragma unroll
    for (int j = 0; j < 4; ++j) rmx[j] = rowmax[srow + j * 32];
    const u16* gb[4];
#pragma unroll
    for (int i = 0; i < 4; ++i) {
        int cc = tid + i * 256;
        int row = cc >> 3;
        int col8 = (cc & 7) ^ (row & 7);
        gb[i] = valsT + ((size_t)h * D + row) * LT + kbeg + col8 * 8;
    }
    const int xorm = (fr & 7) << 4;
    int aOff[2], bOff[2];
#pragma unroll
    for (int s = 0; s < 2; ++s) {
        aOff[s] = ((wr + fr) * 128 + ((kg * 16 + s * 64) ^ xorm)) >> 1;
        bOff[s] = ((wc + fr) * 128 + ((kg * 16 + s * 64) ^ xorm)) >> 1;
    }
    const u16* pa = logits + ((size_t)h * S + m0 + srow) * LT + kbeg + scol8 * 8;
    float sum4[4] = {0.f, 0.f, 0.f, 0.f};
    f32x4 acc[4][4] = {};
    for (int k0 = 0; k0 < K; k0 += 64) {
        uint4 av[4];
#pragma unroll
        for (int j = 0; j < 4; ++j) av[j] = *(const uint4*)(pa + (size_t)j * 32 * LT);
        pa += 64;
#pragma unroll
        for (int i = 0; i < 4; ++i) {
            GLOAD16(gb[i], Bs + (size_t)wid * 512 + i * 2048);
            gb[i] += 64;
        }
        __syncthreads();
#pragma unroll
        for (int j = 0; j < 4; ++j) {
            const u16* q = (const u16*)&av[j];
            float e0 = __expf(bf2f(q[0]) - rmx[j]);
            float e1 = __expf(bf2f(q[1]) - rmx[j]);
            float e2 = __expf(bf2f(q[2]) - rmx[j]);
            float e3 = __expf(bf2f(q[3]) - rmx[j]);
            float e4 = __expf(bf2f(q[4]) - rmx[j]);
            float e5 = __expf(bf2f(q[5]) - rmx[j]);
            float e6 = __expf(bf2f(q[6]) - rmx[j]);
            float e7 = __expf(bf2f(q[7]) - rmx[j]);
            sum4[j] += ((e0 + e1) + (e2 + e3)) + ((e4 + e5) + (e6 + e7));
            uint4 o;
            o.x = pk2(e0, e1, 1.f); o.y = pk2(e2, e3, 1.f);
            o.z = pk2(e4, e5, 1.f); o.w = pk2(e6, e7, 1.f);
            *(uint4*)(As + woff[j]) = o;
        }
        __syncthreads();
#pragma unroll
        for (int s = 0; s < 2; ++s) {
            bf16x8 af[4], bg[4];
#pragma unroll
            for (int i = 0; i < 4; ++i) af[i] = *(const bf16x8*)(As + aOff[s] + i * 1024);
#pragma unroll
            for (int j = 0; j < 4; ++j) bg[j] = *(const bf16x8*)(Bs + bOff[s] + j * 1024);
#pragma unroll
            for (int i = 0; i < 4; ++i)
#pragma unroll
                for (int j = 0; j < 4; ++j)
                    acc[i][j] = __builtin_amdgcn_mfma_f32_16x16x32_bf16(af[i], bg[j], acc[i][j], 0, 0, 0);
        }
        __syncthreads();
    }
#pragma unroll
    for (int j = 0; j < 4; ++j) atomicAdd(&rowsum[srow + j * 32], sum4[j]);
    __syncthreads();
    u16* dst = attp + (size_t)c * S * HID;
#pragma unroll
    for (int i = 0; i < 4; ++i) {
        int r0 = m0 + wr + i * 16 + kg * 4;
#pragma unroll
        for (int j = 0; j < 4; ++j) {
            int cc = h * D + wc + j * 16 + fr;
#pragma unroll
            for (int r = 0; r < 4; ++r)
                dst[(size_t)(r0 + r) * HID + cc] = f2bf(acc[i][j][r]);
        }
    }
    if (tid < 128)
        rowsump[(size_t)c * H * S + (size_t)h * S + m0 + tid] = rowsum[tid];
}

// ---------------- reduce PV partials + normalize by total row sum ----------------
__global__ void pv_reduce(const u16* __restrict__ attp, const float* __restrict__ rowsump,
                          u16* __restrict__ attno, int S) {
    long i = (long)blockIdx.x * 256 + threadIdx.x;    // ushort4 units
    long base = i * 4;
    int s = (int)(base >> 11);                        // /HID
    int cc = (int)(base & 2047);
    int h = cc >> 7;
    int Klim = ((s >> 7) << 7) + 256;
    int n = (Klim + KCH - 1) / KCH;
    long stride4 = (long)S * HID / 4;
    size_t ridx = (size_t)h * S + s;
    float tot = rowsump[ridx];
    ushort4 a = ((const ushort4*)attp)[i];
    float v0 = bf2f(a.x), v1 = bf2f(a.y), v2 = bf2f(a.z), v3 = bf2f(a.w);
    if (n > 1) {
        tot += rowsump[(size_t)H * S + ridx];
        ushort4 b = ((const ushort4*)attp)[i + stride4];
        v0 += bf2f(b.x); v1 += bf2f(b.y); v2 += bf2f(b.z); v3 += bf2f(b.w);
    }
    if (n > 2) {
        tot += rowsump[2 * (size_t)H * S + ridx];
        ushort4 b = ((const ushort4*)attp)[i + 2 * stride4];
        v0 += bf2f(b.x); v1 += bf2f(b.y); v2 += bf2f(b.z); v3 += bf2f(b.w);
    }
    float inv = 1.0f / tot;
    ((ushort4*)attno)[i] = make_ushort4(f2bf(v0 * inv), f2bf(v1 * inv),
                                        f2bf(v2 * inv), f2bf(v3 * inv));
}

// ---------------- out projection split-K x4: bf16 A,B -> f32 partials ----------------
__global__ __launch_bounds__(256, 3) void gemm_out_split(
    const u16* __restrict__ A, const u16* __restrict__ B,
    float* __restrict__ outp, int S)
{
    __shared__ u16 As[8192], Bs[8192];
    int b = blockIdx.y * gridDim.x + blockIdx.x;
    int ntot = gridDim.x * gridDim.y;
    if ((ntot & 7) == 0) { int cpx = ntot >> 3; b = (b & 7) * cpx + (b >> 3); }
    const int m0 = (b / gridDim.x) * 128, n0 = (b % gridDim.x) * 128;
    const int z = blockIdx.z;
    f32x4 acc[4][4] = {};
    mfma_core_128(A + z * 512, HID, B + z * 512, HID, 512, As, Bs, m0, n0, acc);
    const int tid = threadIdx.x, lane = tid & 63, wid = tid >> 6;
    const int wr = (wid >> 1) * 64, wc = (wid & 1) * 64;
    const int fr = lane & 15, kg = lane >> 4;
    float* dst = outp + (size_t)z * S * HID;
#pragma unroll
    for (int i = 0; i < 4; ++i) {
        int r0 = m0 + wr + i * 16 + kg * 4;
#pragma unroll
        for (int j = 0; j < 4; ++j) {
            int c = n0 + wc + j * 16 + fr;
#pragma unroll
            for (int r = 0; r < 4; ++r)
                dst[(size_t)(r0 + r) * HID + c] = acc[i][j][r];
        }
    }
}

__global__ void out_reduce(const float* __restrict__ outp, float* __restrict__ out,
                           long n4) {   // float4 units
    long i = (long)blockIdx.x * 256 + threadIdx.x;
    float4 a = ((const float4*)outp)[i];
    float4 b = ((const float4*)outp)[i + n4];
    float4 c = ((const float4*)outp)[i + 2 * n4];
    float4 d = ((const float4*)outp)[i + 3 * n4];
    ((float4*)out)[i] = make_float4((a.x + b.x) + (c.x + d.x),
                                    (a.y + b.y) + (c.y + d.y),
                                    (a.z + b.z) + (c.z + d.z),
                                    (a.w + b.w) + (c.w + d.w));
}

// ---------------- fused f32 -> bf16 convert over 7 remaining regions ----------------
struct ConvJob {
    const float* src[7];
    u16* dst[7];
    long nchunk[7];
    float sc[7];
    int b0[7];
    int nb[7];
    int nt[7];     // nontemporal-load flag (single-touch source)
};

__device__ __forceinline__ void conv_region16(const float* __restrict__ s,
        u16* __restrict__ d, long nchunk, float sc, int relb, int nb, int ntf) {
    int tid = threadIdx.x;
    for (long c = relb; c < nchunk; c += nb) {
        const f32x4* p = (const f32x4*)s + c * 1024;
        f32x4 v0, v1, v2, v3;
        if (ntf) {
            v0 = __builtin_nontemporal_load(p + tid);
            v1 = __builtin_nontemporal_load(p + tid + 256);
            v2 = __builtin_nontemporal_load(p + tid + 512);
            v3 = __builtin_nontemporal_load(p + tid + 768);
        } else {
            v0 = p[tid]; v1 = p[tid + 256]; v2 = p[tid + 512]; v3 = p[tid + 768];
        }
        uint2* o = (uint2*)d + c * 1024;
        o[tid]       = make_uint2(pk2(v0.x, v0.y, sc), pk2(v0.z, v0.w, sc));
        o[tid + 256] = make_uint2(pk2(v1.x, v1.y, sc), pk2(v1.z, v1.w, sc));
        o[tid + 512] = make_uint2(pk2(v2.x, v2.y, sc), pk2(v2.z, v2.w, sc));
        o[tid + 768] = make_uint2(pk2(v3.x, v3.y, sc), pk2(v3.z, v3.w, sc));
    }
}

__global__ __launch_bounds__(256) void conv_all(ConvJob jb) {
    int b = blockIdx.x;
#define PICKR(r) conv_region16(jb.src[r], jb.dst[r], jb.nchunk[r], jb.sc[r], b - jb.b0[r], jb.nb[r], jb.nt[r])
    if      (b < jb.b0[1]) PICKR(0);
    else if (b < jb.b0[2]) PICKR(1);
    else if (b < jb.b0[3]) PICKR(2);
    else if (b < jb.b0[4]) PICKR(3);
    else if (b < jb.b0[5]) PICKR(4);
    else if (b < jb.b0[6]) PICKR(5);
    else                   PICKR(6);
#undef PICKR
}

__global__ void pack_bias(const float* __restrict__ bq, const float* __restrict__ bk,
                          const float* __restrict__ bv, const float* __restrict__ bq2,
                          float* __restrict__ bp) {
    int i = blockIdx.x * 256 + threadIdx.x;
    if (i >= NQKV) return;
    float v;
    if (i < 2048)      v = bq[i] * SCALE;
    else if (i < 2560) v = bk[i - 2048];
    else if (i < 3072) v = bv[i - 2560];
    else               v = bq2[i - 3072] * SCALE;
    bp[i] = v;
}

// ---------------- RoPE: sincos hoisted per-d, reused across 5 heads per wave ----------------
__global__ __launch_bounds__(256) void rope_bf(u16* __restrict__ qkv,
                                               const int* __restrict__ pos, int S) {
    int s = blockIdx.x;
    float p = (float)pos[s];
    u16* row = qkv + (size_t)s * NQKV;
    int d = threadIdx.x & 63;
    int wg = threadIdx.x >> 6;
    float inv = exp2f(-(float)d * 0.31143075889568833f);   // 1e6^(-d/64)
    float sn, cs; sincosf(p * inv, &sn, &cs);
#pragma unroll
    for (int hh = 0; hh < 5; ++hh) {
        int head = wg * 5 + hh;     // 0..19: q heads 0..15, k heads 16..19
        u16* ptr = row + head * 128 + d;
        float x0 = bf2f(ptr[0]), x1 = bf2f(ptr[64]);
        ptr[0]  = f2bf(x0 * cs - x1 * sn);
        ptr[64] = f2bf(x1 * cs + x0 * sn);
    }
}

// ---------------- fused: stats_reduce + colsum of hs ----------------
__global__ void stats_and_colsum(const float* __restrict__ ps, const float* __restrict__ pss,
                                 float* __restrict__ mu, float* __restrict__ inv, int KB,
                                 const float* __restrict__ hs, float* __restrict__ part, int S) {
    int nb_stats = KB / 256;
    int b = blockIdx.x;
    int tid = threadIdx.x;
    if (b < nb_stats) {
        int i = b * 256 + tid;
        float s = 0.f, ss = 0.f;
#pragma unroll
        for (int c = 0; c < 16; ++c) { s += ps[(size_t)c * KB + i]; ss += pss[(size_t)c * KB + i]; }
        float m  = s * (1.0f / HID);
        float va = ss * (1.0f / HID) - m * m;
        mu[i] = m;
        inv[i] = rsqrtf(va + 1e-5f);
    } else {
        int b2 = b - nb_stats;
        int cx = b2 & 7, ry = b2 >> 3;
        int c = cx * 256 + tid;
        int rows_per = S / 16;
        int r0 = ry * rows_per;
        float a = 0.f;
        for (int r = r0; r < r0 + rows_per; ++r) a += hs[(size_t)r * HID + c];
        part[(size_t)ry * HID + c] = a;
    }
}

__global__ void reduce_part(const float* __restrict__ part, float* __restrict__ out,
                            int nchunk, int ncols) {
    int c = blockIdx.x * 256 + threadIdx.x;
    float a = 0.f;
    for (int i = 0; i < nchunk; ++i) a += part[(size_t)i * ncols + c];
    out[c] = a;
}
__global__ __launch_bounds__(256) void mv_rows(const float* __restrict__ W,
        const float* __restrict__ x, const float* __restrict__ b, float Sb,
        float* __restrict__ y) {
    int row = blockIdx.x * 4 + (threadIdx.x >> 6);
    int lane = threadIdx.x & 63;
    const float4* w4 = (const float4*)(W + (size_t)row * HID);
    const float4* x4 = (const float4*)x;
    float a = 0.f;
#pragma unroll
    for (int c = 0; c < 8; ++c) {
        float4 wv = w4[lane + c * 64], xv = x4[lane + c * 64];
        a += wv.x * xv.x + wv.y * xv.y + wv.z * xv.z + wv.w * xv.w;
    }
    a = wave_red_sum(a);
    if (lane == 0) y[row] = a + Sb * b[row];
}
__global__ void zpart_and_scalars(const float* __restrict__ W, const float* __restrict__ q2s,
                                  float* __restrict__ part, const float* __restrict__ bkn,
                                  float* __restrict__ outs) {
    int b = blockIdx.x;
    int tid = threadIdx.x;
    if (b < 128) {
        int cx = b & 7, ry = b >> 3;
        int e = cx * 256 + tid;
        int r0 = ry * (HID / 16);
        float a = 0.f;
        for (int j = r0; j < r0 + HID / 16; ++j) a += q2s[j] * W[(size_t)j * HID + e];
        part[(size_t)ry * HID + e] = a;
    } else {
        float s1 = 0.f, s2 = 0.f;
        for (int c = tid; c < HID; c += 256) { float v = q2s[c]; s1 += v; s2 += bkn[c] * v; }
        __shared__ float sb[4];
        s1 = block_red_sum(s1, sb);
        s2 = block_red_sum(s2, sb);
        if (tid == 0) { outs[0] = s1; outs[1] = s2; }
    }
}
__global__ __launch_bounds__(256) void kb_scores2(const float* __restrict__ ke,
        const float* __restrict__ z, const float* __restrict__ mu,
        const float* __restrict__ inv, const float* __restrict__ scal2,
        float* __restrict__ sc) {
    int row = blockIdx.x * 4 + (threadIdx.x >> 6);
    int lane = threadIdx.x & 63;
    const float4* x4 = (const float4*)(ke + (size_t)row * HID);
    const float4* z4 = (const float4*)z;
    float a = 0.f;
#pragma unroll
    for (int c = 0; c < 8; ++c) {
        float4 xv = x4[lane + c * 64], zv = z4[lane + c * 64];
        a += xv.x * zv.x + xv.y * zv.y + xv.z * zv.z + xv.w * zv.w;
    }
    a = wave_red_sum(a);
    if (lane == 0) sc[row] = SCALE * inv[row] * ((a + scal2[1]) - mu[row] * scal2[0]);
}

// ---------------- top-k: 2D-tiled partial ranks (jax tie semantics) ----------------
__global__ __launch_bounds__(256) void topk_rank_part(
    const float* __restrict__ sc, int* __restrict__ prank, int KB) {
    __shared__ float sj[256];
    int tid = threadIdx.x;
    int i = blockIdx.x * 256 + tid;
    int j0 = blockIdx.y * 256;
    sj[tid] = sc[j0 + tid];
    __syncthreads();
    float si = sc[i];
    int jrel = i - j0;
    int r = 0;
#pragma unroll 8
    for (int j = 0; j < 256; ++j) {
        float v = sj[j];
        r += (v > si) || (v == si && j < jrel);
    }
    prank[(size_t)blockIdx.y * KB + i] = r;
}

// ---------------- merged: flags from partial ranks + ascending compaction ----------------
__global__ void topk_finish(const int* __restrict__ prank, int* __restrict__ idx,
                            int nchunk, int KB) {
    __shared__ int flg[4096];
    int tid = threadIdx.x;
    for (int i = tid; i < KB; i += 256) {
        int r = 0;
        for (int c = 0; c < nchunk; ++c) r += prank[(size_t)c * KB + i];
        flg[i] = (r < TOPK) ? 1 : 0;
    }
    __syncthreads();
    if (tid < 64) {
        int lane = tid;
        int base = 0;
        for (int c = 0; c < KB; c += 64) {
            int f = flg[c + lane];
            unsigned long long m = __ballot(f != 0);
            if (f) idx[base + __popcll(m & ((1ull << lane) - 1ull))] = c + lane;
            base += (int)__popcll(m);
        }
    }
}

// ---------------- gather+convert the 128 selected keme / vame rows ----------------
__global__ __launch_bounds__(256) void gather_sel(
    const float* __restrict__ keme, const float* __restrict__ vame,
    const int* __restrict__ idx, u16* __restrict__ ksel, u16* __restrict__ vsel) {
    int t = blockIdx.x;
    int g = idx[t];
    int tid = threadIdx.x;
    const float4* pk = (const float4*)(keme + (size_t)g * HID);
    const float4* pv = (const float4*)(vame + (size_t)g * HID);
    float4 a0 = pk[tid], a1 = pk[tid + 256];
    float4 b0 = pv[tid], b1 = pv[tid + 256];
    uint2* dk = (uint2*)(ksel + (size_t)t * HID);
    uint2* dv = (uint2*)(vsel + (size_t)t * HID);
    dk[tid]       = make_uint2(pk2(a0.x, a0.y, 1.f), pk2(a0.z, a0.w, 1.f));
    dk[tid + 256] = make_uint2(pk2(a1.x, a1.y, 1.f), pk2(a1.z, a1.w, 1.f));
    dv[tid]       = make_uint2(pk2(b0.x, b0.y, 1.f), pk2(b0.z, b0.w, 1.f));
    dv[tid + 256] = make_uint2(pk2(b1.x, b1.y, 1.f), pk2(b1.z, b1.w, 1.f));
}

// ---------------- build valsT[h][d][k] = concat(kbvsel, v)[k][h*D+d] ----------------
__global__ __launch_bounds__(256) void build_valsT(
    const u16* __restrict__ kbvsel, const u16* __restrict__ qkv,
    u16* __restrict__ valsT, int S)
{
    const int h = blockIdx.y, k0 = blockIdx.x * 64;
    const int LT = TOPK + S;
    __shared__ u16 t[64][136];
    int tid = threadIdx.x;
#pragma unroll
    for (int r = 0; r < 4; ++r) {
        int f = tid + r * 256;
        int kk = f >> 4, c8 = (f & 15) * 8;
        int kg = k0 + kk;
        const u16* src;
        if (kg < TOPK) src = kbvsel + (size_t)kg * HID + h * D + c8;
        else           src = qkv + (size_t)(kg - TOPK) * NQKV + 2560 + (h >> 2) * D + c8;
        *(uint4*)&t[kk][c8] = *(const uint4*)src;
    }
    __syncthreads();
    int d = tid >> 1, kh = (tid & 1) * 32;
    u16* dst = valsT + ((size_t)h * D + d) * LT + k0 + kh;
#pragma unroll
    for (int i = 0; i < 8; ++i) {
        ushort4 o = make_ushort4(t[kh + i*4 + 0][d], t[kh + i*4 + 1][d],
                                 t[kh + i*4 + 2][d], t[kh + i*4 + 3][d]);
        *(ushort4*)(dst + i * 4) = o;
    }
}

extern "C" void kernel_launch(void* const* d_in, const int* in_sizes, int n_in,
                              void* d_out, int out_size, void* d_ws, size_t ws_size,
                              hipStream_t stream) {
    const float* hs   = (const float*)d_in[0];
    const float* keme = (const float*)d_in[1];
    const float* vame = (const float*)d_in[2];
    const int*   pos  = (const int*)d_in[3];
    const float* Wq   = (const float*)d_in[4];
    const float* bq   = (const float*)d_in[5];
    const float* Wk   = (const float*)d_in[6];
    const float* bk_  = (const float*)d_in[7];
    const float* Wv   = (const float*)d_in[8];
    const float* bv   = (const float*)d_in[9];
    const float* Wq2  = (const float*)d_in[10];
    const float* bq2  = (const float*)d_in[11];
    const float* Wkn  = (const float*)d_in[12];
    const float* bkn  = (const float*)d_in[13];
    const float* Wvn  = (const float*)d_in[14];
    const float* bvn  = (const float*)d_in[15];
    const float* Wo   = (const float*)d_in[16];
    float* out = (float*)d_out;

    const int S  = in_sizes[3];
    const int KB = in_sizes[1] / HID;
    const int LT = TOPK + S;
    const int NS = S / 128;

    char* w = (char*)d_ws;
    auto carve = [&](size_t bytes) { char* p = w; w += (bytes + 255) & ~(size_t)255; return p; };
    u16* hsbf   = (u16*)carve((size_t)S * HID * 2);
    u16* kebf   = (u16*)carve((size_t)KB * HID * 2);
    u16* wpack  = (u16*)carve((size_t)NQKV * HID * 2);
    u16* wknbf  = (u16*)carve((size_t)HID * HID * 2);
    u16* wvnbf  = (u16*)carve((size_t)HID * HID * 2);
    u16* wobf   = (u16*)carve((size_t)HID * HID * 2);
    float* bpk  = (float*)carve(NQKV * 4);
    u16* qkv    = (u16*)carve((size_t)S * NQKV * 2);
    float* mu   = (float*)carve((size_t)KB * 4);
    float* inv  = (float*)carve((size_t)KB * 4);
    float* part_s  = (float*)carve((size_t)16 * KB * 4);
    float* part_ss = (float*)carve((size_t)16 * KB * 4);
    u16* logits = (u16*)carve((size_t)H * S * LT * 2);
    u16* valsT  = (u16*)carve((size_t)H * D * LT * 2);
    u16* attp   = (u16*)carve((size_t)3 * S * HID * 2);
    u16* attno  = (u16*)carve((size_t)S * HID * 2);
    float* outp = (float*)carve((size_t)4 * S * HID * 4);
    float* rmaxpart = (float*)carve((size_t)H * S * 10 * 4);
    float* rowsump = (float*)carve((size_t)3 * H * S * 4);
    u16* ksel   = (u16*)carve((size_t)TOPK * HID * 2);
    u16* vsel   = (u16*)carve((size_t)TOPK * HID * 2);
    u16* kbksel = (u16*)carve((size_t)TOPK * HID * 2);
    u16* kbvsel = (u16*)carve((size_t)TOPK * HID * 2);
    float* hsum = (float*)carve(HID * 4);
    float* q2s  = (float*)carve(HID * 4);
    float* zv   = (float*)carve(HID * 4);
    float* part = (float*)carve((size_t)16 * HID * 4);
    float* scal2= (float*)carve(2 * 4);
    float* sc   = (float*)carve((size_t)KB * 4);
    int* prank  = (int*)carve((size_t)(KB / 256) * KB * 4);
    int* idx    = (int*)carve(TOPK * 4);

    // ---- fused convert dispatch: 7 regions (Wvn, Wo deferred into GEMM dispatches) ----
    ConvJob jb;
    const float* srcs[7] = {hs, keme, Wq, Wk, Wv, Wq2, Wkn};
    u16* dsts[7] = {hsbf, kebf, wpack, wpack + (size_t)2048 * HID,
                    wpack + (size_t)2560 * HID, wpack + (size_t)3072 * HID,
                    wknbf};
    long nel[7] = {(long)S * HID, (long)KB * HID,
                   (long)HID * HID, (long)512 * HID, (long)512 * HID,
                   (long)HID * HID, (long)HID * HID};
    float scls[7] = {1.f, 1.f, SCALE, 1.f, 1.f, SCALE, 1.f};
    int ntfs[7] = {0, 0, 1, 1, 1, 0, 0};
    long totc = 0;
    for (int r = 0; r < 7; ++r) totc += nel[r] / 4096;
    int btot = 0;
    for (int r = 0; r < 7; ++r) {
        long nch = nel[r] / 4096;
        int nb = (int)((2048.0 * (double)nch) / (double)totc + 0.5);
        if (nb < 1) nb = 1;
        jb.src[r] = srcs[r]; jb.dst[r] = dsts[r]; jb.nchunk[r] = nch;
        jb.sc[r] = scls[r]; jb.b0[r] = btot; jb.nb[r] = nb; jb.nt[r] = ntfs[r];
        btot += nb;
    }
    conv_all<<<btot, 256, 0, stream>>>(jb);
    pack_bias<<<NQKV / 256, 256, 0, stream>>>(bq, bk_, bv, bq2, bpk);

    // ---- merged projections (QKV + KB-stats) + appended Wvn conversion ----
    int nproj = (NQKV / 128) * (S / 128) + (HID / 128) * (KB / 128);
    gemm_proj_all<<<nproj + 256, 256, 0, stream>>>(
        hsbf, wpack, bpk, qkv, kebf, wknbf, bkn, part_s, part_ss, S, KB,
        Wvn, wvnbf);

    rope_bf<<<S, 256, 0, stream>>>(qkv, pos, S);
    stats_and_colsum<<<KB / 256 + 128, 256, 0, stream>>>(
        part_s, part_ss, mu, inv, KB, hs, part, S);
    reduce_part<<<HID / 256, 256, 0, stream>>>(part, hsum, 16, HID);
    mv_rows<<<HID / 4, 256, 0, stream>>>(Wq2, hsum, bq2, (float)S, q2s);
    zpart_and_scalars<<<129, 256, 0, stream>>>(Wkn, q2s, part, bkn, scal2);
    reduce_part<<<HID / 256, 256, 0, stream>>>(part, zv, 16, HID);
    kb_scores2<<<KB / 4, 256, 0, stream>>>(keme, zv, mu, inv, scal2, sc);

    // ---- top-k + ascending compaction (merged finish) ----
    topk_rank_part<<<dim3(KB / 256, KB / 256), 256, 0, stream>>>(sc, prank, KB);
    topk_finish<<<1, 256, 0, stream>>>(prank, idx, KB / 256, KB);

    // ---- selected rows: gather+convert, pair GEMM (kbk w/ LN, kbv) ----
    gather_sel<<<TOPK, 256, 0, stream>>>(keme, vame, idx, ksel, vsel);
    gemm_sel_pair<<<dim3(HID / 128, 1, 2), 256, 0, stream>>>(
        ksel, vsel, wknbf, wvnbf, bkn, bvn, mu, inv, idx, kbksel, kbvsel);

    build_valsT<<<dim3(LT / 64, H), 256, 0, stream>>>(kbvsel, qkv, valsT, S);

    // ---- logits (+ per-tile row maxes) + appended Wo conversion ----
    logits_all<<<dim3(NS * (NS + 1) / 2 + NS + 16, H), 256, 0, stream>>>(
        qkv, kbksel, logits, rmaxpart, S, Wo, wobf);

    // ---- PV with inline exp + inline rmax combine, then reduce/normalize ----
    pv_exp_split<<<dim3(S / 128, H, 3), 256, 0, stream>>>(
        logits, valsT, rmaxpart, attp, rowsump, S);
    pv_reduce<<<(int)((size_t)S * HID / 1024), 256, 0, stream>>>(
        attp, rowsump, attno, S);

    // ---- output projection (split-K x4 + reduce) ----
    gemm_out_split<<<dim3(HID / 128, S / 128, 4), 256, 0, stream>>>(
        attno, wobf, outp, S);
    out_reduce<<<(int)((size_t)S * HID / 1024), 256, 0, stream>>>(
        outp, out, (long)S * HID / 4);
}

// Round 15
// 318.633 us; speedup vs baseline: 1.1364x; 1.1364x over previous
//
#include <hip/hip_runtime.h>
#include <hip/hip_bf16.h>
#include <math.h>

#define H 16
#define KVH 4
#define D 128
#define HID 2048
#define TOPK 128
#define NQKV 5120   // 2048 q + 512 k + 512 v + 2048 q2
#define SCALE 0.088388347648318447f
#define KCH 384     // PV K-split chunk

typedef __attribute__((ext_vector_type(8))) short bf16x8;
typedef __attribute__((ext_vector_type(4))) float f32x4;
typedef unsigned short u16;

__device__ __forceinline__ float bf2f(u16 u) {
    return __uint_as_float(((unsigned)u) << 16);
}
__device__ __forceinline__ u16 f2bf(float f) {
    unsigned x = __float_as_uint(f);
    x += 0x7fffu + ((x >> 16) & 1u);   // RNE
    return (u16)(x >> 16);
}
__device__ __forceinline__ unsigned pk2(float a, float b, float sc) {
    return (unsigned)f2bf(a * sc) | ((unsigned)f2bf(b * sc) << 16);
}

__device__ __forceinline__ float wave_red_sum(float v) {
#pragma unroll
    for (int o = 32; o > 0; o >>= 1) v += __shfl_xor(v, o, 64);
    return v;
}
__device__ __forceinline__ float block_red_sum(float v, float* sb) {
    v = wave_red_sum(v);
    int w = threadIdx.x >> 6;
    if ((threadIdx.x & 63) == 0) sb[w] = v;
    __syncthreads();
    float r = (sb[0] + sb[1]) + (sb[2] + sb[3]);
    __syncthreads();
    return r;
}

#define GLOAD16(g, l) __builtin_amdgcn_global_load_lds( \
    (const __attribute__((address_space(1))) void*)(g), \
    (__attribute__((address_space(3))) void*)(l), 16, 0, 0)

// convert one 256th of a HID*HID f32 weight to bf16 (16 f32x4 / thread)
__device__ __forceinline__ void conv_w_block(const float* __restrict__ src,
        u16* __restrict__ dst, int cidx) {
    const f32x4* p = (const f32x4*)src;
    uint2* o = (uint2*)dst;
    long base = (long)cidx * 4096;
#pragma unroll
    for (int it = 0; it < 16; ++it) {
        long i = base + it * 256 + threadIdx.x;
        f32x4 v = __builtin_nontemporal_load(p + i);
        o[i] = make_uint2(pk2(v.x, v.y, 1.f), pk2(v.z, v.w, 1.f));
    }
}

// ---------------- shared MFMA core: 128x128 C-tile, BK=64, 4 waves ----------------
__device__ __forceinline__ void mfma_core_128(
    const u16* A, int lda, const u16* B, int ldb, int K,
    u16* As, u16* Bs, int m0, int n0, f32x4 (&acc)[4][4])
{
    const int tid = threadIdx.x;
    const int lane = tid & 63, wid = tid >> 6;
    const int wr = (wid >> 1) * 64, wc = (wid & 1) * 64;
    const int fr = lane & 15, kg = lane >> 4;

    const u16* ga[4]; const u16* gb[4];
#pragma unroll
    for (int i = 0; i < 4; ++i) {
        int c = tid + i * 256;
        int row = c >> 3;
        int col8 = (c & 7) ^ (row & 7);
        ga[i] = A + (size_t)(m0 + row) * lda + col8 * 8;
        gb[i] = B + (size_t)(n0 + row) * ldb + col8 * 8;
    }
    const int xorm = (fr & 7) << 4;
    const int sA0 = ((wr + fr) * 128 + (((kg * 16)     ) ^ xorm)) >> 1;
    const int sA1 = ((wr + fr) * 128 + (((kg * 16) + 64) ^ xorm)) >> 1;
    const int sB0 = ((wc + fr) * 128 + (((kg * 16)     ) ^ xorm)) >> 1;
    const int sB1 = ((wc + fr) * 128 + (((kg * 16) + 64) ^ xorm)) >> 1;

    for (int k0 = 0; k0 < K; k0 += 64) {
#pragma unroll
        for (int i = 0; i < 4; ++i) {
            GLOAD16(ga[i], As + (size_t)wid * 512 + i * 2048);  // +lane*16B implicit
            GLOAD16(gb[i], Bs + (size_t)wid * 512 + i * 2048);
            ga[i] += 64; gb[i] += 64;
        }
        __syncthreads();
#pragma unroll
        for (int s = 0; s < 2; ++s) {
            const int oA = s ? sA1 : sA0;
            const int oB = s ? sB1 : sB0;
            bf16x8 af[4], bg[4];
#pragma unroll
            for (int i = 0; i < 4; ++i) af[i] = *(const bf16x8*)(As + oA + i * 1024);
#pragma unroll
            for (int j = 0; j < 4; ++j) bg[j] = *(const bf16x8*)(Bs + oB + j * 1024);
#pragma unroll
            for (int i = 0; i < 4; ++i)
#pragma unroll
                for (int j = 0; j < 4; ++j)
                    acc[i][j] = __builtin_amdgcn_mfma_f32_16x16x32_bf16(af[i], bg[j], acc[i][j], 0, 0, 0);
        }
        __syncthreads();
    }
}

__device__ __forceinline__ void gemm_epilogue_bf16(
    f32x4 (&acc)[4][4], const float* bias, u16* C, int ldc, int m0, int n0)
{
    const int tid = threadIdx.x, lane = tid & 63, wid = tid >> 6;
    const int wr = (wid >> 1) * 64, wc = (wid & 1) * 64;
    const int fr = lane & 15, kg = lane >> 4;
#pragma unroll
    for (int i = 0; i < 4; ++i) {
        int r0 = m0 + wr + i * 16 + kg * 4;
#pragma unroll
        for (int j = 0; j < 4; ++j) {
            int c = n0 + wc + j * 16 + fr;
            float bb = bias ? bias[c] : 0.0f;
#pragma unroll
            for (int r = 0; r < 4; ++r)
                C[(size_t)(r0 + r) * ldc + c] = f2bf(acc[i][j][r] + bb);
        }
    }
}

// ---------------- MERGED: QKV proj + KB-stats GEMM (+appended Wvn conversion) ----------------
__global__ __launch_bounds__(256, 3) void gemm_proj_all(
    const u16* __restrict__ hsbf, const u16* __restrict__ wpack,
    const float* __restrict__ bpk, u16* __restrict__ qkv,
    const u16* __restrict__ kebf, const u16* __restrict__ wknbf,
    const float* __restrict__ bkn,
    float* __restrict__ part_s, float* __restrict__ part_ss, int S, int KB,
    const float* __restrict__ Wvn, u16* __restrict__ wvnbf)
{
    __shared__ u16 As[8192], Bs[8192];
    __shared__ float sred[2][128], ssred[2][128];
    const int nqkvb = (NQKV / 128) * (S / 128);
    const int ntot = nqkvb + (HID / 128) * (KB / 128);
    int b = blockIdx.x;
    if (b >= ntot) {              // appended blocks: convert Wvn (overlaps GEMM)
        conv_w_block(Wvn, wvnbf, b - ntot);
        return;
    }
    if ((ntot & 7) == 0) { int cpx = ntot >> 3; b = (b & 7) * cpx + (b >> 3); }
    f32x4 acc[4][4] = {};
    const int tid = threadIdx.x, lane = tid & 63, wid = tid >> 6;
    const int wr = (wid >> 1) * 64, wc = (wid & 1) * 64;
    const int fr = lane & 15, kg = lane >> 4;
    if (b < nqkvb) {
        int bx = b % (NQKV / 128), by = b / (NQKV / 128);
        int m0 = by * 128, n0 = bx * 128;
        mfma_core_128(hsbf, HID, wpack, HID, HID, As, Bs, m0, n0, acc);
        gemm_epilogue_bf16(acc, bpk, qkv, NQKV, m0, n0);
    } else {
        int b2 = b - nqkvb;
        int bx = b2 & 15, by = b2 >> 4;
        int m0 = by * 128, n0 = bx * 128;
        mfma_core_128(kebf, HID, wknbf, HID, HID, As, Bs, m0, n0, acc);
#pragma unroll
        for (int i = 0; i < 4; ++i) {
            float rs[4] = {0.f, 0.f, 0.f, 0.f}, rss[4] = {0.f, 0.f, 0.f, 0.f};
#pragma unroll
            for (int j = 0; j < 4; ++j) {
                float bb = bkn[n0 + wc + j * 16 + fr];
#pragma unroll
                for (int r = 0; r < 4; ++r) {
                    float v = acc[i][j][r] + bb;
                    rs[r] += v; rss[r] += v * v;
                }
            }
#pragma unroll
            for (int o = 1; o < 16; o <<= 1) {
#pragma unroll
                for (int r = 0; r < 4; ++r) {
                    rs[r]  += __shfl_xor(rs[r],  o, 64);
                    rss[r] += __shfl_xor(rss[r], o, 64);
                }
            }
            if (fr == 0) {
#pragma unroll
                for (int r = 0; r < 4; ++r) {
                    sred[wid & 1][wr + i * 16 + kg * 4 + r]  = rs[r];
                    ssred[wid & 1][wr + i * 16 + kg * 4 + r] = rss[r];
                }
            }
        }
        __syncthreads();
        if (tid < 128) {
            part_s[(size_t)bx * KB + m0 + tid]  = sred[0][tid] + sred[1][tid];
            part_ss[(size_t)bx * KB + m0 + tid] = ssred[0][tid] + ssred[1][tid];
        }
    }
}

// ---------------- selected-row pair GEMM (bf16): z=0 kbk(LN), z=1 kbv ----------------
__global__ __launch_bounds__(256, 3) void gemm_sel_pair(
    const u16* __restrict__ ksel, const u16* __restrict__ vsel,
    const u16* __restrict__ Bk, const u16* __restrict__ Bv,
    const float* __restrict__ bkn, const float* __restrict__ bvn,
    const float* __restrict__ mu, const float* __restrict__ inv,
    const int* __restrict__ idx, u16* __restrict__ Ck, u16* __restrict__ Cv)
{
    __shared__ u16 As[8192], Bs[8192];
    const int z = blockIdx.z;
    const u16* A = z ? vsel : ksel;
    const u16* B = z ? Bv : Bk;
    const float* bias = z ? bvn : bkn;
    u16* C = z ? Cv : Ck;
    const int n0 = blockIdx.x * 128;
    f32x4 acc[4][4] = {};
    mfma_core_128(A, HID, B, HID, HID, As, Bs, 0, n0, acc);
    const int tid = threadIdx.x, lane = tid & 63, wid = tid >> 6;
    const int wr = (wid >> 1) * 64, wc = (wid & 1) * 64;
    const int fr = lane & 15, kg = lane >> 4;
#pragma unroll
    for (int i = 0; i < 4; ++i) {
        int r0 = wr + i * 16 + kg * 4;
#pragma unroll
        for (int j = 0; j < 4; ++j) {
            int c = n0 + wc + j * 16 + fr;
            float bb = bias[c];
#pragma unroll
            for (int r = 0; r < 4; ++r) {
                float v = acc[i][j][r] + bb;
                if (z == 0) {
                    int g = idx[r0 + r];
                    v = (v - mu[g]) * inv[g];
                }
                C[(size_t)(r0 + r) * HID + c] = f2bf(v);
            }
        }
    }
}

// ---------------- MERGED logits + per-tile row max emission ----------------
__global__ __launch_bounds__(256, 3) void logits_all(
    const u16* __restrict__ qkv, const u16* __restrict__ kbksel,
    u16* __restrict__ logits, float* __restrict__ rmaxpart, int S)
{
    __shared__ u16 As[8192], Bs[8192];
    __shared__ float rex[2][128];
    const int h = blockIdx.y;
    const int NS = S >> 7;
    const int npairs = NS * (NS + 1) / 2;
    const int LT = TOPK + S;
    int x = blockIdx.x;
    f32x4 acc[4][4] = {};
    const int tid = threadIdx.x, lane = tid & 63, wid = tid >> 6;
    const int wr = (wid >> 1) * 64, wc = (wid & 1) * 64;
    const int fr = lane & 15, kg = lane >> 4;
    float pmax[4][4];
#pragma unroll
    for (int i = 0; i < 4; ++i)
#pragma unroll
        for (int r = 0; r < 4; ++r) pmax[i][r] = -3.0e38f;
    int rowbase, tslot;
    if (x < npairs) {
        int s0t = 0;
        while ((s0t + 1) * (s0t + 2) / 2 <= x) ++s0t;
        int j0t = x - s0t * (s0t + 1) / 2;
        int s0 = s0t * 128, j0 = j0t * 128;
        mfma_core_128(qkv + h * D, NQKV, qkv + HID + (h >> 2) * D, NQKV, D,
                      As, Bs, s0, j0, acc);
#pragma unroll
        for (int i = 0; i < 4; ++i) {
            int r0 = s0 + wr + i * 16 + kg * 4;
#pragma unroll
            for (int j = 0; j < 4; ++j) {
                int c = j0 + wc + j * 16 + fr;
#pragma unroll
                for (int r = 0; r < 4; ++r) {
                    float v = (c <= r0 + r) ? acc[i][j][r] : -1.0e30f;
                    pmax[i][r] = fmaxf(pmax[i][r], v);
                    logits[((size_t)h * S + r0 + r) * LT + TOPK + c] = f2bf(v);
                }
            }
        }
        rowbase = s0; tslot = j0t + 1;
    } else {
        int m0 = (x - npairs) * 128;
        mfma_core_128(qkv + 3072 + h * D, NQKV, kbksel + h * D, HID, D,
                      As, Bs, m0, 0, acc);
#pragma unroll
        for (int i = 0; i < 4; ++i) {
            int r0 = m0 + wr + i * 16 + kg * 4;
#pragma unroll
            for (int j = 0; j < 4; ++j) {
                int c = wc + j * 16 + fr;
#pragma unroll
                for (int r = 0; r < 4; ++r) {
                    float v = acc[i][j][r];
                    pmax[i][r] = fmaxf(pmax[i][r], v);
                    logits[((size_t)h * S + r0 + r) * LT + c] = f2bf(v);
                }
            }
        }
        rowbase = m0; tslot = 0;
    }
#pragma unroll
    for (int o = 1; o < 16; o <<= 1)
#pragma unroll
        for (int i = 0; i < 4; ++i)
#pragma unroll
            for (int r = 0; r < 4; ++r)
                pmax[i][r] = fmaxf(pmax[i][r], __shfl_xor(pmax[i][r], o, 64));
    __syncthreads();
    if (fr == 0) {
#pragma unroll
        for (int i = 0; i < 4; ++i)
#pragma unroll
            for (int r = 0; r < 4; ++r)
                rex[wid & 1][wr + i * 16 + kg * 4 + r] = pmax[i][r];
    }
    __syncthreads();
    if (tid < 128)
        rmaxpart[((size_t)h * S + rowbase + tid) * 10 + tslot] =
            fmaxf(rex[0][tid], rex[1][tid]);
}

// ---------------- PV K-split with inline exp (+inline rmax combine) ----------------
__global__ __launch_bounds__(256, 3) void pv_exp_split(
    const u16* __restrict__ logits, const u16* __restrict__ valsT,
    const float* __restrict__ rmaxpart, u16* __restrict__ attp,
    float* __restrict__ rowsump, int S)
{
    const int m0 = blockIdx.x * 128, h = blockIdx.y, c = blockIdx.z;
    const int LT = TOPK + S;
    const int Klim = TOPK + m0 + 128;
    const int kbeg = c * KCH;
    if (kbeg >= Klim) return;
    const int K = min(KCH, Klim - kbeg);
    __shared__ u16 As[8192], Bs[8192];
    __shared__ float rowsum[128];
    __shared__ float rowmax[128];
    const int tid = threadIdx.x, lane = tid & 63, wid = tid >> 6;
    const int wr = (wid >> 1) * 64, wc = (wid & 1) * 64;
    const int fr = lane & 15, kg = lane >> 4;
    const int srow = tid >> 3, scol8 = tid & 7;
    if (tid < 128) {
        rowsum[tid] = 0.f;
        int s = m0 + tid;
        int ntt = (s >> 7) + 2;
        const float* rp = rmaxpart + ((size_t)h * S + s) * 10;
        float m = -3.0e38f;
        for (int t = 0; t < ntt; ++t) m = fmaxf(m, rp[t]);
        rowmax[tid] = m;
    }
    int woff[4];
#pragma unroll
    for (int j = 0; j < 4; ++j) {
        int row = srow + j * 32;
        woff[j] = (row * 128 + ((scol8 * 16) ^ ((row & 7) * 16))) >> 1;
    }
    __syncthreads();
    float rmx[4];
#pragma unroll
    for (int j = 0; j < 4; ++j) rmx[j] = rowmax[srow + j * 32];
    const u16* gb[4];
#pragma unroll
    for (int i = 0; i < 4; ++i) {
        int cc = tid + i * 256;
        int row = cc >> 3;
        int col8 = (cc & 7) ^ (row & 7);
        gb[i] = valsT + ((size_t)h * D + row) * LT + kbeg + col8 * 8;
    }
    const int xorm = (fr & 7) << 4;
    int aOff[2], bOff[2];
#pragma unroll
    for (int s = 0; s < 2; ++s) {
        aOff[s] = ((wr + fr) * 128 + ((kg * 16 + s * 64) ^ xorm)) >> 1;
        bOff[s] = ((wc + fr) * 128 + ((kg * 16 + s * 64) ^ xorm)) >> 1;
    }
    const u16* pa = logits + ((size_t)h * S + m0 + srow) * LT + kbeg + scol8 * 8;
    float sum4[4] = {0.f, 0.f, 0.f, 0.f};
    f32x4 acc[4][4] = {};
    for (int k0 = 0; k0 < K; k0 += 64) {
        uint4 av[4];
#pragma unroll
        for (int j = 0; j < 4; ++j) av[j] = *(const uint4*)(pa + (size_t)j * 32 * LT);
        pa += 64;
#pragma unroll
        for (int i = 0; i < 4; ++i) {
            GLOAD16(gb[i], Bs + (size_t)wid * 512 + i * 2048);
            gb[i] += 64;
        }
        __syncthreads();
#pragma unroll
        for (int j = 0; j < 4; ++j) {
            const u16* q = (const u16*)&av[j];
            float e0 = __expf(bf2f(q[0]) - rmx[j]);
            float e1 = __expf(bf2f(q[1]) - rmx[j]);
            float e2 = __expf(bf2f(q[2]) - rmx[j]);
            float e3 = __expf(bf2f(q[3]) - rmx[j]);
            float e4 = __expf(bf2f(q[4]) - rmx[j]);
            float e5 = __expf(bf2f(q[5]) - rmx[j]);
            float e6 = __expf(bf2f(q[6]) - rmx[j]);
            float e7 = __expf(bf2f(q[7]) - rmx[j]);
            sum4[j] += ((e0 + e1) + (e2 + e3)) + ((e4 + e5) + (e6 + e7));
            uint4 o;
            o.x = pk2(e0, e1, 1.f); o.y = pk2(e2, e3, 1.f);
            o.z = pk2(e4, e5, 1.f); o.w = pk2(e6, e7, 1.f);
            *(uint4*)(As + woff[j]) = o;
        }
        __syncthreads();
#pragma unroll
        for (int s = 0; s < 2; ++s) {
            bf16x8 af[4], bg[4];
#pragma unroll
            for (int i = 0; i < 4; ++i) af[i] = *(const bf16x8*)(As + aOff[s] + i * 1024);
#pragma unroll
            for (int j = 0; j < 4; ++j) bg[j] = *(const bf16x8*)(Bs + bOff[s] + j * 1024);
#pragma unroll
            for (int i = 0; i < 4; ++i)
#pragma unroll
                for (int j = 0; j < 4; ++j)
                    acc[i][j] = __builtin_amdgcn_mfma_f32_16x16x32_bf16(af[i], bg[j], acc[i][j], 0, 0, 0);
        }
        __syncthreads();
    }
#pragma unroll
    for (int j = 0; j < 4; ++j) atomicAdd(&rowsum[srow + j * 32], sum4[j]);
    __syncthreads();
    u16* dst = attp + (size_t)c * S * HID;
#pragma unroll
    for (int i = 0; i < 4; ++i) {
        int r0 = m0 + wr + i * 16 + kg * 4;
#pragma unroll
        for (int j = 0; j < 4; ++j) {
            int cc = h * D + wc + j * 16 + fr;
#pragma unroll
            for (int r = 0; r < 4; ++r)
                dst[(size_t)(r0 + r) * HID + cc] = f2bf(acc[i][j][r]);
        }
    }
    if (tid < 128)
        rowsump[(size_t)c * H * S + (size_t)h * S + m0 + tid] = rowsum[tid];
}

// ---------------- reduce PV partials + normalize by total row sum ----------------
__global__ void pv_reduce(const u16* __restrict__ attp, const float* __restrict__ rowsump,
                          u16* __restrict__ attno, int S) {
    long i = (long)blockIdx.x * 256 + threadIdx.x;    // ushort4 units
    long base = i * 4;
    int s = (int)(base >> 11);                        // /HID
    int cc = (int)(base & 2047);
    int h = cc >> 7;
    int Klim = ((s >> 7) << 7) + 256;
    int n = (Klim + KCH - 1) / KCH;
    long stride4 = (long)S * HID / 4;
    size_t ridx = (size_t)h * S + s;
    float tot = rowsump[ridx];
    ushort4 a = ((const ushort4*)attp)[i];
    float v0 = bf2f(a.x), v1 = bf2f(a.y), v2 = bf2f(a.z), v3 = bf2f(a.w);
    if (n > 1) {
        tot += rowsump[(size_t)H * S + ridx];
        ushort4 b = ((const ushort4*)attp)[i + stride4];
        v0 += bf2f(b.x); v1 += bf2f(b.y); v2 += bf2f(b.z); v3 += bf2f(b.w);
    }
    if (n > 2) {
        tot += rowsump[2 * (size_t)H * S + ridx];
        ushort4 b = ((const ushort4*)attp)[i + 2 * stride4];
        v0 += bf2f(b.x); v1 += bf2f(b.y); v2 += bf2f(b.z); v3 += bf2f(b.w);
    }
    float inv = 1.0f / tot;
    ((ushort4*)attno)[i] = make_ushort4(f2bf(v0 * inv), f2bf(v1 * inv),
                                        f2bf(v2 * inv), f2bf(v3 * inv));
}

// ---------------- out projection split-K x4: bf16 A,B -> f32 partials ----------------
__global__ __launch_bounds__(256, 3) void gemm_out_split(
    const u16* __restrict__ A, const u16* __restrict__ B,
    float* __restrict__ outp, int S)
{
    __shared__ u16 As[8192], Bs[8192];
    int b = blockIdx.y * gridDim.x + blockIdx.x;
    int ntot = gridDim.x * gridDim.y;
    if ((ntot & 7) == 0) { int cpx = ntot >> 3; b = (b & 7) * cpx + (b >> 3); }
    const int m0 = (b / gridDim.x) * 128, n0 = (b % gridDim.x) * 128;
    const int z = blockIdx.z;
    f32x4 acc[4][4] = {};
    mfma_core_128(A + z * 512, HID, B + z * 512, HID, 512, As, Bs, m0, n0, acc);
    const int tid = threadIdx.x, lane = tid & 63, wid = tid >> 6;
    const int wr = (wid >> 1) * 64, wc = (wid & 1) * 64;
    const int fr = lane & 15, kg = lane >> 4;
    float* dst = outp + (size_t)z * S * HID;
#pragma unroll
    for (int i = 0; i < 4; ++i) {
        int r0 = m0 + wr + i * 16 + kg * 4;
#pragma unroll
        for (int j = 0; j < 4; ++j) {
            int c = n0 + wc + j * 16 + fr;
#pragma unroll
            for (int r = 0; r < 4; ++r)
                dst[(size_t)(r0 + r) * HID + c] = acc[i][j][r];
        }
    }
}

__global__ void out_reduce(const float* __restrict__ outp, float* __restrict__ out,
                           long n4) {   // float4 units
    long i = (long)blockIdx.x * 256 + threadIdx.x;
    float4 a = ((const float4*)outp)[i];
    float4 b = ((const float4*)outp)[i + n4];
    float4 c = ((const float4*)outp)[i + 2 * n4];
    float4 d = ((const float4*)outp)[i + 3 * n4];
    ((float4*)out)[i] = make_float4((a.x + b.x) + (c.x + d.x),
                                    (a.y + b.y) + (c.y + d.y),
                                    (a.z + b.z) + (c.z + d.z),
                                    (a.w + b.w) + (c.w + d.w));
}

// ---------------- fused f32 -> bf16 convert over 8 regions (Wvn deferred) ----------------
struct ConvJob {
    const float* src[8];
    u16* dst[8];
    long nchunk[8];
    float sc[8];
    int b0[8];
    int nb[8];
    int nt[8];     // nontemporal-load flag (single-touch source)
};

__device__ __forceinline__ void conv_region16(const float* __restrict__ s,
        u16* __restrict__ d, long nchunk, float sc, int relb, int nb, int ntf) {
    int tid = threadIdx.x;
    for (long c = relb; c < nchunk; c += nb) {
        const f32x4* p = (const f32x4*)s + c * 1024;
        f32x4 v0, v1, v2, v3;
        if (ntf) {
            v0 = __builtin_nontemporal_load(p + tid);
            v1 = __builtin_nontemporal_load(p + tid + 256);
            v2 = __builtin_nontemporal_load(p + tid + 512);
            v3 = __builtin_nontemporal_load(p + tid + 768);
        } else {
            v0 = p[tid]; v1 = p[tid + 256]; v2 = p[tid + 512]; v3 = p[tid + 768];
        }
        uint2* o = (uint2*)d + c * 1024;
        o[tid]       = make_uint2(pk2(v0.x, v0.y, sc), pk2(v0.z, v0.w, sc));
        o[tid + 256] = make_uint2(pk2(v1.x, v1.y, sc), pk2(v1.z, v1.w, sc));
        o[tid + 512] = make_uint2(pk2(v2.x, v2.y, sc), pk2(v2.z, v2.w, sc));
        o[tid + 768] = make_uint2(pk2(v3.x, v3.y, sc), pk2(v3.z, v3.w, sc));
    }
}

__global__ __launch_bounds__(256) void conv_all(ConvJob jb) {
    int b = blockIdx.x;
#define PICKR(r) conv_region16(jb.src[r], jb.dst[r], jb.nchunk[r], jb.sc[r], b - jb.b0[r], jb.nb[r], jb.nt[r])
    if      (b < jb.b0[1]) PICKR(0);
    else if (b < jb.b0[2]) PICKR(1);
    else if (b < jb.b0[3]) PICKR(2);
    else if (b < jb.b0[4]) PICKR(3);
    else if (b < jb.b0[5]) PICKR(4);
    else if (b < jb.b0[6]) PICKR(5);
    else if (b < jb.b0[7]) PICKR(6);
    else                   PICKR(7);
#undef PICKR
}

__global__ void pack_bias(const float* __restrict__ bq, const float* __restrict__ bk,
                          const float* __restrict__ bv, const float* __restrict__ bq2,
                          float* __restrict__ bp) {
    int i = blockIdx.x * 256 + threadIdx.x;
    if (i >= NQKV) return;
    float v;
    if (i < 2048)      v = bq[i] * SCALE;
    else if (i < 2560) v = bk[i - 2048];
    else if (i < 3072) v = bv[i - 2560];
    else               v = bq2[i - 3072] * SCALE;
    bp[i] = v;
}

// ---------------- RoPE: sincos hoisted per-d, reused across 5 heads per wave ----------------
__global__ __launch_bounds__(256) void rope_bf(u16* __restrict__ qkv,
                                               const int* __restrict__ pos, int S) {
    int s = blockIdx.x;
    float p = (float)pos[s];
    u16* row = qkv + (size_t)s * NQKV;
    int d = threadIdx.x & 63;
    int wg = threadIdx.x >> 6;
    float inv = exp2f(-(float)d * 0.31143075889568833f);   // 1e6^(-d/64)
    float sn, cs; sincosf(p * inv, &sn, &cs);
#pragma unroll
    for (int hh = 0; hh < 5; ++hh) {
        int head = wg * 5 + hh;     // 0..19: q heads 0..15, k heads 16..19
        u16* ptr = row + head * 128 + d;
        float x0 = bf2f(ptr[0]), x1 = bf2f(ptr[64]);
        ptr[0]  = f2bf(x0 * cs - x1 * sn);
        ptr[64] = f2bf(x1 * cs + x0 * sn);
    }
}

// ---------------- fused: stats_reduce + colsum of hs ----------------
__global__ void stats_and_colsum(const float* __restrict__ ps, const float* __restrict__ pss,
                                 float* __restrict__ mu, float* __restrict__ inv, int KB,
                                 const float* __restrict__ hs, float* __restrict__ part, int S) {
    int nb_stats = KB / 256;
    int b = blockIdx.x;
    int tid = threadIdx.x;
    if (b < nb_stats) {
        int i = b * 256 + tid;
        float s = 0.f, ss = 0.f;
#pragma unroll
        for (int c = 0; c < 16; ++c) { s += ps[(size_t)c * KB + i]; ss += pss[(size_t)c * KB + i]; }
        float m  = s * (1.0f / HID);
        float va = ss * (1.0f / HID) - m * m;
        mu[i] = m;
        inv[i] = rsqrtf(va + 1e-5f);
    } else {
        int b2 = b - nb_stats;
        int cx = b2 & 7, ry = b2 >> 3;
        int c = cx * 256 + tid;
        int rows_per = S / 16;
        int r0 = ry * rows_per;
        float a = 0.f;
        for (int r = r0; r < r0 + rows_per; ++r) a += hs[(size_t)r * HID + c];
        part[(size_t)ry * HID + c] = a;
    }
}

__global__ void reduce_part(const float* __restrict__ part, float* __restrict__ out,
                            int nchunk, int ncols) {
    int c = blockIdx.x * 256 + threadIdx.x;
    float a = 0.f;
    for (int i = 0; i < nchunk; ++i) a += part[(size_t)i * ncols + c];
    out[c] = a;
}
__global__ __launch_bounds__(256) void mv_rows(const float* __restrict__ W,
        const float* __restrict__ x, const float* __restrict__ b, float Sb,
        float* __restrict__ y) {
    int row = blockIdx.x * 4 + (threadIdx.x >> 6);
    int lane = threadIdx.x & 63;
    const float4* w4 = (const float4*)(W + (size_t)row * HID);
    const float4* x4 = (const float4*)x;
    float a = 0.f;
#pragma unroll
    for (int c = 0; c < 8; ++c) {
        float4 wv = w4[lane + c * 64], xv = x4[lane + c * 64];
        a += wv.x * xv.x + wv.y * xv.y + wv.z * xv.z + wv.w * xv.w;
    }
    a = wave_red_sum(a);
    if (lane == 0) y[row] = a + Sb * b[row];
}
__global__ void zpart_and_scalars(const float* __restrict__ W, const float* __restrict__ q2s,
                                  float* __restrict__ part, const float* __restrict__ bkn,
                                  float* __restrict__ outs) {
    int b = blockIdx.x;
    int tid = threadIdx.x;
    if (b < 128) {
        int cx = b & 7, ry = b >> 3;
        int e = cx * 256 + tid;
        int r0 = ry * (HID / 16);
        float a = 0.f;
        for (int j = r0; j < r0 + HID / 16; ++j) a += q2s[j] * W[(size_t)j * HID + e];
        part[(size_t)ry * HID + e] = a;
    } else {
        float s1 = 0.f, s2 = 0.f;
        for (int c = tid; c < HID; c += 256) { float v = q2s[c]; s1 += v; s2 += bkn[c] * v; }
        __shared__ float sb[4];
        s1 = block_red_sum(s1, sb);
        s2 = block_red_sum(s2, sb);
        if (tid == 0) { outs[0] = s1; outs[1] = s2; }
    }
}
__global__ __launch_bounds__(256) void kb_scores2(const float* __restrict__ ke,
        const float* __restrict__ z, const float* __restrict__ mu,
        const float* __restrict__ inv, const float* __restrict__ scal2,
        float* __restrict__ sc) {
    int row = blockIdx.x * 4 + (threadIdx.x >> 6);
    int lane = threadIdx.x & 63;
    const float4* x4 = (const float4*)(ke + (size_t)row * HID);
    const float4* z4 = (const float4*)z;
    float a = 0.f;
#pragma unroll
    for (int c = 0; c < 8; ++c) {
        float4 xv = x4[lane + c * 64], zv = z4[lane + c * 64];
        a += xv.x * zv.x + xv.y * zv.y + xv.z * zv.z + xv.w * zv.w;
    }
    a = wave_red_sum(a);
    if (lane == 0) sc[row] = SCALE * inv[row] * ((a + scal2[1]) - mu[row] * scal2[0]);
}

// ---------------- top-k: 2D-tiled partial ranks (jax tie semantics) ----------------
__global__ __launch_bounds__(256) void topk_rank_part(
    const float* __restrict__ sc, int* __restrict__ prank, int KB) {
    __shared__ float sj[256];
    int tid = threadIdx.x;
    int i = blockIdx.x * 256 + tid;
    int j0 = blockIdx.y * 256;
    sj[tid] = sc[j0 + tid];
    __syncthreads();
    float si = sc[i];
    int jrel = i - j0;
    int r = 0;
#pragma unroll 8
    for (int j = 0; j < 256; ++j) {
        float v = sj[j];
        r += (v > si) || (v == si && j < jrel);
    }
    prank[(size_t)blockIdx.y * KB + i] = r;
}
__global__ void topk_flags2(const int* __restrict__ prank, int* __restrict__ flg,
                            int nchunk, int KB) {
    int i = blockIdx.x * 256 + threadIdx.x;
    int r = 0;
    for (int c = 0; c < nchunk; ++c) r += prank[(size_t)c * KB + i];
    flg[i] = (r < TOPK) ? 1 : 0;
}
__global__ void compact_idx(const int* __restrict__ flg, int* __restrict__ idx, int KB) {
    int lane = threadIdx.x;
    int base = 0;
    for (int c = 0; c < KB; c += 64) {
        int f = flg[c + lane];
        unsigned long long m = __ballot(f != 0);
        if (f) idx[base + __popcll(m & ((1ull << lane) - 1ull))] = c + lane;
        base += (int)__popcll(m);
    }
}

// ---------------- gather+convert the 128 selected keme / vame rows ----------------
__global__ __launch_bounds__(256) void gather_sel(
    const float* __restrict__ keme, const float* __restrict__ vame,
    const int* __restrict__ idx, u16* __restrict__ ksel, u16* __restrict__ vsel) {
    int t = blockIdx.x;
    int g = idx[t];
    int tid = threadIdx.x;
    const float4* pk = (const float4*)(keme + (size_t)g * HID);
    const float4* pv = (const float4*)(vame + (size_t)g * HID);
    float4 a0 = pk[tid], a1 = pk[tid + 256];
    float4 b0 = pv[tid], b1 = pv[tid + 256];
    uint2* dk = (uint2*)(ksel + (size_t)t * HID);
    uint2* dv = (uint2*)(vsel + (size_t)t * HID);
    dk[tid]       = make_uint2(pk2(a0.x, a0.y, 1.f), pk2(a0.z, a0.w, 1.f));
    dk[tid + 256] = make_uint2(pk2(a1.x, a1.y, 1.f), pk2(a1.z, a1.w, 1.f));
    dv[tid]       = make_uint2(pk2(b0.x, b0.y, 1.f), pk2(b0.z, b0.w, 1.f));
    dv[tid + 256] = make_uint2(pk2(b1.x, b1.y, 1.f), pk2(b1.z, b1.w, 1.f));
}

// ---------------- build valsT[h][d][k] = concat(kbvsel, v)[k][h*D+d] ----------------
__global__ __launch_bounds__(256) void build_valsT(
    const u16* __restrict__ kbvsel, const u16* __restrict__ qkv,
    u16* __restrict__ valsT, int S)
{
    const int h = blockIdx.y, k0 = blockIdx.x * 64;
    const int LT = TOPK + S;
    __shared__ u16 t[64][136];
    int tid = threadIdx.x;
#pragma unroll
    for (int r = 0; r < 4; ++r) {
        int f = tid + r * 256;
        int kk = f >> 4, c8 = (f & 15) * 8;
        int kg = k0 + kk;
        const u16* src;
        if (kg < TOPK) src = kbvsel + (size_t)kg * HID + h * D + c8;
        else           src = qkv + (size_t)(kg - TOPK) * NQKV + 2560 + (h >> 2) * D + c8;
        *(uint4*)&t[kk][c8] = *(const uint4*)src;
    }
    __syncthreads();
    int d = tid >> 1, kh = (tid & 1) * 32;
    u16* dst = valsT + ((size_t)h * D + d) * LT + k0 + kh;
#pragma unroll
    for (int i = 0; i < 8; ++i) {
        ushort4 o = make_ushort4(t[kh + i*4 + 0][d], t[kh + i*4 + 1][d],
                                 t[kh + i*4 + 2][d], t[kh + i*4 + 3][d]);
        *(ushort4*)(dst + i * 4) = o;
    }
}

extern "C" void kernel_launch(void* const* d_in, const int* in_sizes, int n_in,
                              void* d_out, int out_size, void* d_ws, size_t ws_size,
                              hipStream_t stream) {
    const float* hs   = (const float*)d_in[0];
    const float* keme = (const float*)d_in[1];
    const float* vame = (const float*)d_in[2];
    const int*   pos  = (const int*)d_in[3];
    const float* Wq   = (const float*)d_in[4];
    const float* bq   = (const float*)d_in[5];
    const float* Wk   = (const float*)d_in[6];
    const float* bk_  = (const float*)d_in[7];
    const float* Wv   = (const float*)d_in[8];
    const float* bv   = (const float*)d_in[9];
    const float* Wq2  = (const float*)d_in[10];
    const float* bq2  = (const float*)d_in[11];
    const float* Wkn  = (const float*)d_in[12];
    const float* bkn  = (const float*)d_in[13];
    const float* Wvn  = (const float*)d_in[14];
    const float* bvn  = (const float*)d_in[15];
    const float* Wo   = (const float*)d_in[16];
    float* out = (float*)d_out;

    const int S  = in_sizes[3];
    const int KB = in_sizes[1] / HID;
    const int LT = TOPK + S;
    const int NS = S / 128;

    char* w = (char*)d_ws;
    auto carve = [&](size_t bytes) { char* p = w; w += (bytes + 255) & ~(size_t)255; return p; };
    u16* hsbf   = (u16*)carve((size_t)S * HID * 2);
    u16* kebf   = (u16*)carve((size_t)KB * HID * 2);
    u16* wpack  = (u16*)carve((size_t)NQKV * HID * 2);
    u16* wknbf  = (u16*)carve((size_t)HID * HID * 2);
    u16* wvnbf  = (u16*)carve((size_t)HID * HID * 2);
    u16* wobf   = (u16*)carve((size_t)HID * HID * 2);
    float* bpk  = (float*)carve(NQKV * 4);
    u16* qkv    = (u16*)carve((size_t)S * NQKV * 2);
    float* mu   = (float*)carve((size_t)KB * 4);
    float* inv  = (float*)carve((size_t)KB * 4);
    float* part_s  = (float*)carve((size_t)16 * KB * 4);
    float* part_ss = (float*)carve((size_t)16 * KB * 4);
    u16* logits = (u16*)carve((size_t)H * S * LT * 2);
    u16* valsT  = (u16*)carve((size_t)H * D * LT * 2);
    u16* attp   = (u16*)carve((size_t)3 * S * HID * 2);
    u16* attno  = (u16*)carve((size_t)S * HID * 2);
    float* outp = (float*)carve((size_t)4 * S * HID * 4);
    float* rmaxpart = (float*)carve((size_t)H * S * 10 * 4);
    float* rowsump = (float*)carve((size_t)3 * H * S * 4);
    u16* ksel   = (u16*)carve((size_t)TOPK * HID * 2);
    u16* vsel   = (u16*)carve((size_t)TOPK * HID * 2);
    u16* kbksel = (u16*)carve((size_t)TOPK * HID * 2);
    u16* kbvsel = (u16*)carve((size_t)TOPK * HID * 2);
    float* hsum = (float*)carve(HID * 4);
    float* q2s  = (float*)carve(HID * 4);
    float* zv   = (float*)carve(HID * 4);
    float* part = (float*)carve((size_t)16 * HID * 4);
    float* scal2= (float*)carve(2 * 4);
    float* sc   = (float*)carve((size_t)KB * 4);
    int* prank  = (int*)carve((size_t)(KB / 256) * KB * 4);
    int* flg    = (int*)carve((size_t)KB * 4);
    int* idx    = (int*)carve(TOPK * 4);

    // ---- fused convert dispatch: 8 regions (Wvn deferred into proj dispatch) ----
    ConvJob jb;
    const float* srcs[8] = {hs, keme, Wq, Wk, Wv, Wq2, Wkn, Wo};
    u16* dsts[8] = {hsbf, kebf, wpack, wpack + (size_t)2048 * HID,
                    wpack + (size_t)2560 * HID, wpack + (size_t)3072 * HID,
                    wknbf, wobf};
    long nel[8] = {(long)S * HID, (long)KB * HID,
                   (long)HID * HID, (long)512 * HID, (long)512 * HID,
                   (long)HID * HID, (long)HID * HID, (long)HID * HID};
    float scls[8] = {1.f, 1.f, SCALE, 1.f, 1.f, SCALE, 1.f, 1.f};
    int ntfs[8] = {0, 0, 1, 1, 1, 0, 0, 1};
    long totc = 0;
    for (int r = 0; r < 8; ++r) totc += nel[r] / 4096;
    int btot = 0;
    for (int r = 0; r < 8; ++r) {
        long nch = nel[r] / 4096;
        int nb = (int)((2048.0 * (double)nch) / (double)totc + 0.5);
        if (nb < 1) nb = 1;
        jb.src[r] = srcs[r]; jb.dst[r] = dsts[r]; jb.nchunk[r] = nch;
        jb.sc[r] = scls[r]; jb.b0[r] = btot; jb.nb[r] = nb; jb.nt[r] = ntfs[r];
        btot += nb;
    }
    conv_all<<<btot, 256, 0, stream>>>(jb);
    pack_bias<<<NQKV / 256, 256, 0, stream>>>(bq, bk_, bv, bq2, bpk);

    // ---- merged projections (QKV + KB-stats) + appended Wvn conversion ----
    int nproj = (NQKV / 128) * (S / 128) + (HID / 128) * (KB / 128);
    gemm_proj_all<<<nproj + 256, 256, 0, stream>>>(
        hsbf, wpack, bpk, qkv, kebf, wknbf, bkn, part_s, part_ss, S, KB,
        Wvn, wvnbf);

    rope_bf<<<S, 256, 0, stream>>>(qkv, pos, S);
    stats_and_colsum<<<KB / 256 + 128, 256, 0, stream>>>(
        part_s, part_ss, mu, inv, KB, hs, part, S);
    reduce_part<<<HID / 256, 256, 0, stream>>>(part, hsum, 16, HID);
    mv_rows<<<HID / 4, 256, 0, stream>>>(Wq2, hsum, bq2, (float)S, q2s);
    zpart_and_scalars<<<129, 256, 0, stream>>>(Wkn, q2s, part, bkn, scal2);
    reduce_part<<<HID / 256, 256, 0, stream>>>(part, zv, 16, HID);
    kb_scores2<<<KB / 4, 256, 0, stream>>>(keme, zv, mu, inv, scal2, sc);

    // ---- top-k + ascending compaction (parallel flags) ----
    topk_rank_part<<<dim3(KB / 256, KB / 256), 256, 0, stream>>>(sc, prank, KB);
    topk_flags2<<<KB / 256, 256, 0, stream>>>(prank, flg, KB / 256, KB);
    compact_idx<<<1, 64, 0, stream>>>(flg, idx, KB);

    // ---- selected rows: gather+convert, pair GEMM (kbk w/ LN, kbv) ----
    gather_sel<<<TOPK, 256, 0, stream>>>(keme, vame, idx, ksel, vsel);
    gemm_sel_pair<<<dim3(HID / 128, 1, 2), 256, 0, stream>>>(
        ksel, vsel, wknbf, wvnbf, bkn, bvn, mu, inv, idx, kbksel, kbvsel);

    build_valsT<<<dim3(LT / 64, H), 256, 0, stream>>>(kbvsel, qkv, valsT, S);

    // ---- logits (+ per-tile row maxes) ----
    logits_all<<<dim3(NS * (NS + 1) / 2 + NS, H), 256, 0, stream>>>(
        qkv, kbksel, logits, rmaxpart, S);

    // ---- PV with inline exp + inline rmax combine, then reduce/normalize ----
    pv_exp_split<<<dim3(S / 128, H, 3), 256, 0, stream>>>(
        logits, valsT, rmaxpart, attp, rowsump, S);
    pv_reduce<<<(int)((size_t)S * HID / 1024), 256, 0, stream>>>(
        attp, rowsump, attno, S);

    // ---- output projection (split-K x4 + reduce) ----
    gemm_out_split<<<dim3(HID / 128, S / 128, 4), 256, 0, stream>>>(
        attno, wobf, outp, S);
    out_reduce<<<(int)((size_t)S * HID / 1024), 256, 0, stream>>>(
        outp, out, (long)S * HID / 4);
}

// Round 16
// 313.937 us; speedup vs baseline: 1.1534x; 1.0150x over previous
//
#include <hip/hip_runtime.h>
#include <hip/hip_bf16.h>
#include <math.h>

#define H 16
#define KVH 4
#define D 128
#define HID 2048
#define TOPK 128
#define NQKV 5120   // 2048 q + 512 k + 512 v + 2048 q2
#define SCALE 0.088388347648318447f
#define KCH 384     // PV K-split chunk

typedef __attribute__((ext_vector_type(8))) short bf16x8;
typedef __attribute__((ext_vector_type(4))) float f32x4;
typedef unsigned short u16;

__device__ __forceinline__ float bf2f(u16 u) {
    return __uint_as_float(((unsigned)u) << 16);
}
__device__ __forceinline__ u16 f2bf(float f) {
    unsigned x = __float_as_uint(f);
    x += 0x7fffu + ((x >> 16) & 1u);   // RNE
    return (u16)(x >> 16);
}
__device__ __forceinline__ unsigned pk2(float a, float b, float sc) {
    return (unsigned)f2bf(a * sc) | ((unsigned)f2bf(b * sc) << 16);
}

__device__ __forceinline__ float wave_red_sum(float v) {
#pragma unroll
    for (int o = 32; o > 0; o >>= 1) v += __shfl_xor(v, o, 64);
    return v;
}
__device__ __forceinline__ float block_red_sum(float v, float* sb) {
    v = wave_red_sum(v);
    int w = threadIdx.x >> 6;
    if ((threadIdx.x & 63) == 0) sb[w] = v;
    __syncthreads();
    float r = (sb[0] + sb[1]) + (sb[2] + sb[3]);
    __syncthreads();
    return r;
}

#define GLOAD16(g, l) __builtin_amdgcn_global_load_lds( \
    (const __attribute__((address_space(1))) void*)(g), \
    (__attribute__((address_space(3))) void*)(l), 16, 0, 0)

// convert one 256th of a HID*HID f32 weight to bf16 (16 f32x4 / thread)
__device__ __forceinline__ void conv_w_block(const float* __restrict__ src,
        u16* __restrict__ dst, int cidx) {
    const f32x4* p = (const f32x4*)src;
    uint2* o = (uint2*)dst;
    long base = (long)cidx * 4096;
#pragma unroll
    for (int it = 0; it < 16; ++it) {
        long i = base + it * 256 + threadIdx.x;
        f32x4 v = __builtin_nontemporal_load(p + i);
        o[i] = make_uint2(pk2(v.x, v.y, 1.f), pk2(v.z, v.w, 1.f));
    }
}

// ---------------- shared MFMA core: 128x128 C-tile, BK=64, 4 waves ----------------
__device__ __forceinline__ void mfma_core_128(
    const u16* A, int lda, const u16* B, int ldb, int K,
    u16* As, u16* Bs, int m0, int n0, f32x4 (&acc)[4][4])
{
    const int tid = threadIdx.x;
    const int lane = tid & 63, wid = tid >> 6;
    const int wr = (wid >> 1) * 64, wc = (wid & 1) * 64;
    const int fr = lane & 15, kg = lane >> 4;

    const u16* ga[4]; const u16* gb[4];
#pragma unroll
    for (int i = 0; i < 4; ++i) {
        int c = tid + i * 256;
        int row = c >> 3;
        int col8 = (c & 7) ^ (row & 7);
        ga[i] = A + (size_t)(m0 + row) * lda + col8 * 8;
        gb[i] = B + (size_t)(n0 + row) * ldb + col8 * 8;
    }
    const int xorm = (fr & 7) << 4;
    const int sA0 = ((wr + fr) * 128 + (((kg * 16)     ) ^ xorm)) >> 1;
    const int sA1 = ((wr + fr) * 128 + (((kg * 16) + 64) ^ xorm)) >> 1;
    const int sB0 = ((wc + fr) * 128 + (((kg * 16)     ) ^ xorm)) >> 1;
    const int sB1 = ((wc + fr) * 128 + (((kg * 16) + 64) ^ xorm)) >> 1;

    for (int k0 = 0; k0 < K; k0 += 64) {
#pragma unroll
        for (int i = 0; i < 4; ++i) {
            GLOAD16(ga[i], As + (size_t)wid * 512 + i * 2048);  // +lane*16B implicit
            GLOAD16(gb[i], Bs + (size_t)wid * 512 + i * 2048);
            ga[i] += 64; gb[i] += 64;
        }
        __syncthreads();
#pragma unroll
        for (int s = 0; s < 2; ++s) {
            const int oA = s ? sA1 : sA0;
            const int oB = s ? sB1 : sB0;
            bf16x8 af[4], bg[4];
#pragma unroll
            for (int i = 0; i < 4; ++i) af[i] = *(const bf16x8*)(As + oA + i * 1024);
#pragma unroll
            for (int j = 0; j < 4; ++j) bg[j] = *(const bf16x8*)(Bs + oB + j * 1024);
#pragma unroll
            for (int i = 0; i < 4; ++i)
#pragma unroll
                for (int j = 0; j < 4; ++j)
                    acc[i][j] = __builtin_amdgcn_mfma_f32_16x16x32_bf16(af[i], bg[j], acc[i][j], 0, 0, 0);
        }
        __syncthreads();
    }
}

__device__ __forceinline__ void gemm_epilogue_bf16(
    f32x4 (&acc)[4][4], const float* bias, u16* C, int ldc, int m0, int n0)
{
    const int tid = threadIdx.x, lane = tid & 63, wid = tid >> 6;
    const int wr = (wid >> 1) * 64, wc = (wid & 1) * 64;
    const int fr = lane & 15, kg = lane >> 4;
#pragma unroll
    for (int i = 0; i < 4; ++i) {
        int r0 = m0 + wr + i * 16 + kg * 4;
#pragma unroll
        for (int j = 0; j < 4; ++j) {
            int c = n0 + wc + j * 16 + fr;
            float bb = bias ? bias[c] : 0.0f;
#pragma unroll
            for (int r = 0; r < 4; ++r)
                C[(size_t)(r0 + r) * ldc + c] = f2bf(acc[i][j][r] + bb);
        }
    }
}

// ---------------- MERGED: QKV proj + KB-stats GEMM (+appended Wvn conversion) ----------------
__global__ __launch_bounds__(256, 3) void gemm_proj_all(
    const u16* __restrict__ hsbf, const u16* __restrict__ wpack,
    const float* __restrict__ bpk, u16* __restrict__ qkv,
    const u16* __restrict__ kebf, const u16* __restrict__ wknbf,
    const float* __restrict__ bkn,
    float* __restrict__ part_s, float* __restrict__ part_ss, int S, int KB,
    const float* __restrict__ Wvn, u16* __restrict__ wvnbf)
{
    __shared__ u16 As[8192], Bs[8192];
    __shared__ float sred[2][128], ssred[2][128];
    const int nqkvb = (NQKV / 128) * (S / 128);
    const int ntot = nqkvb + (HID / 128) * (KB / 128);
    int b = blockIdx.x;
    if (b >= ntot) {              // appended blocks: convert Wvn (overlaps GEMM)
        conv_w_block(Wvn, wvnbf, b - ntot);
        return;
    }
    if ((ntot & 7) == 0) { int cpx = ntot >> 3; b = (b & 7) * cpx + (b >> 3); }
    f32x4 acc[4][4] = {};
    const int tid = threadIdx.x, lane = tid & 63, wid = tid >> 6;
    const int wr = (wid >> 1) * 64, wc = (wid & 1) * 64;
    const int fr = lane & 15, kg = lane >> 4;
    if (b < nqkvb) {
        int bx = b % (NQKV / 128), by = b / (NQKV / 128);
        int m0 = by * 128, n0 = bx * 128;
        mfma_core_128(hsbf, HID, wpack, HID, HID, As, Bs, m0, n0, acc);
        gemm_epilogue_bf16(acc, bpk, qkv, NQKV, m0, n0);
    } else {
        int b2 = b - nqkvb;
        int bx = b2 & 15, by = b2 >> 4;
        int m0 = by * 128, n0 = bx * 128;
        mfma_core_128(kebf, HID, wknbf, HID, HID, As, Bs, m0, n0, acc);
#pragma unroll
        for (int i = 0; i < 4; ++i) {
            float rs[4] = {0.f, 0.f, 0.f, 0.f}, rss[4] = {0.f, 0.f, 0.f, 0.f};
#pragma unroll
            for (int j = 0; j < 4; ++j) {
                float bb = bkn[n0 + wc + j * 16 + fr];
#pragma unroll
                for (int r = 0; r < 4; ++r) {
                    float v = acc[i][j][r] + bb;
                    rs[r] += v; rss[r] += v * v;
                }
            }
#pragma unroll
            for (int o = 1; o < 16; o <<= 1) {
#pragma unroll
                for (int r = 0; r < 4; ++r) {
                    rs[r]  += __shfl_xor(rs[r],  o, 64);
                    rss[r] += __shfl_xor(rss[r], o, 64);
                }
            }
            if (fr == 0) {
#pragma unroll
                for (int r = 0; r < 4; ++r) {
                    sred[wid & 1][wr + i * 16 + kg * 4 + r]  = rs[r];
                    ssred[wid & 1][wr + i * 16 + kg * 4 + r] = rss[r];
                }
            }
        }
        __syncthreads();
        if (tid < 128) {
            part_s[(size_t)bx * KB + m0 + tid]  = sred[0][tid] + sred[1][tid];
            part_ss[(size_t)bx * KB + m0 + tid] = ssred[0][tid] + ssred[1][tid];
        }
    }
}

// ---------------- selected-row pair GEMM (bf16): z=0 kbk(LN), z=1 kbv ----------------
__global__ __launch_bounds__(256, 3) void gemm_sel_pair(
    const u16* __restrict__ ksel, const u16* __restrict__ vsel,
    const u16* __restrict__ Bk, const u16* __restrict__ Bv,
    const float* __restrict__ bkn, const float* __restrict__ bvn,
    const float* __restrict__ mu, const float* __restrict__ inv,
    const int* __restrict__ idx, u16* __restrict__ Ck, u16* __restrict__ Cv)
{
    __shared__ u16 As[8192], Bs[8192];
    const int z = blockIdx.z;
    const u16* A = z ? vsel : ksel;
    const u16* B = z ? Bv : Bk;
    const float* bias = z ? bvn : bkn;
    u16* C = z ? Cv : Ck;
    const int n0 = blockIdx.x * 128;
    f32x4 acc[4][4] = {};
    mfma_core_128(A, HID, B, HID, HID, As, Bs, 0, n0, acc);
    const int tid = threadIdx.x, lane = tid & 63, wid = tid >> 6;
    const int wr = (wid >> 1) * 64, wc = (wid & 1) * 64;
    const int fr = lane & 15, kg = lane >> 4;
#pragma unroll
    for (int i = 0; i < 4; ++i) {
        int r0 = wr + i * 16 + kg * 4;
#pragma unroll
        for (int j = 0; j < 4; ++j) {
            int c = n0 + wc + j * 16 + fr;
            float bb = bias[c];
#pragma unroll
            for (int r = 0; r < 4; ++r) {
                float v = acc[i][j][r] + bb;
                if (z == 0) {
                    int g = idx[r0 + r];
                    v = (v - mu[g]) * inv[g];
                }
                C[(size_t)(r0 + r) * HID + c] = f2bf(v);
            }
        }
    }
}

// ---------------- MERGED logits: writes p = exp(s) directly (fixed-reference softmax,
// M = 0; valid since |s| << f32/bf16 range and softmax is shift-invariant),
// plus per-tile row SUM partials for later normalization ----------------
__global__ __launch_bounds__(256, 3) void logits_all(
    const u16* __restrict__ qkv, const u16* __restrict__ kbksel,
    u16* __restrict__ probs, float* __restrict__ rsumpart, int S)
{
    __shared__ u16 As[8192], Bs[8192];
    __shared__ float rex[2][128];
    const int h = blockIdx.y;
    const int NS = S >> 7;
    const int npairs = NS * (NS + 1) / 2;
    const int LT = TOPK + S;
    int x = blockIdx.x;
    f32x4 acc[4][4] = {};
    const int tid = threadIdx.x, lane = tid & 63, wid = tid >> 6;
    const int wr = (wid >> 1) * 64, wc = (wid & 1) * 64;
    const int fr = lane & 15, kg = lane >> 4;
    float psum[4][4];
#pragma unroll
    for (int i = 0; i < 4; ++i)
#pragma unroll
        for (int r = 0; r < 4; ++r) psum[i][r] = 0.f;
    int rowbase, tslot;
    if (x < npairs) {
        int s0t = 0;
        while ((s0t + 1) * (s0t + 2) / 2 <= x) ++s0t;
        int j0t = x - s0t * (s0t + 1) / 2;
        int s0 = s0t * 128, j0 = j0t * 128;
        mfma_core_128(qkv + h * D, NQKV, qkv + HID + (h >> 2) * D, NQKV, D,
                      As, Bs, s0, j0, acc);
#pragma unroll
        for (int i = 0; i < 4; ++i) {
            int r0 = s0 + wr + i * 16 + kg * 4;
#pragma unroll
            for (int j = 0; j < 4; ++j) {
                int c = j0 + wc + j * 16 + fr;
#pragma unroll
                for (int r = 0; r < 4; ++r) {
                    float e = (c <= r0 + r) ? __expf(acc[i][j][r]) : 0.0f;
                    psum[i][r] += e;
                    probs[((size_t)h * S + r0 + r) * LT + TOPK + c] = f2bf(e);
                }
            }
        }
        rowbase = s0; tslot = j0t + 1;
    } else {
        int m0 = (x - npairs) * 128;
        mfma_core_128(qkv + 3072 + h * D, NQKV, kbksel + h * D, HID, D,
                      As, Bs, m0, 0, acc);
#pragma unroll
        for (int i = 0; i < 4; ++i) {
            int r0 = m0 + wr + i * 16 + kg * 4;
#pragma unroll
            for (int j = 0; j < 4; ++j) {
                int c = wc + j * 16 + fr;
#pragma unroll
                for (int r = 0; r < 4; ++r) {
                    float e = __expf(acc[i][j][r]);
                    psum[i][r] += e;
                    probs[((size_t)h * S + r0 + r) * LT + c] = f2bf(e);
                }
            }
        }
        rowbase = m0; tslot = 0;
    }
    // sum across the 16 fr lanes (covers all 64 cols of this wave half with j-loop)
#pragma unroll
    for (int o = 1; o < 16; o <<= 1)
#pragma unroll
        for (int i = 0; i < 4; ++i)
#pragma unroll
            for (int r = 0; r < 4; ++r)
                psum[i][r] += __shfl_xor(psum[i][r], o, 64);
    __syncthreads();
    if (fr == 0) {
#pragma unroll
        for (int i = 0; i < 4; ++i)
#pragma unroll
            for (int r = 0; r < 4; ++r)
                rex[wid & 1][wr + i * 16 + kg * 4 + r] = psum[i][r];
    }
    __syncthreads();
    if (tid < 128)
        rsumpart[((size_t)h * S + rowbase + tid) * 10 + tslot] =
            rex[0][tid] + rex[1][tid];
}

// ---------------- PV K-split: plain GEMM over p (no exp, no rmax) ----------------
__global__ __launch_bounds__(256, 3) void pv_split(
    const u16* __restrict__ probs, const u16* __restrict__ valsT,
    u16* __restrict__ attp, int S)
{
    const int m0 = blockIdx.x * 128, h = blockIdx.y, c = blockIdx.z;
    const int LT = TOPK + S;
    const int Klim = TOPK + m0 + 128;
    const int kbeg = c * KCH;
    if (kbeg >= Klim) return;
    const int K = min(KCH, Klim - kbeg);
    __shared__ u16 As[8192], Bs[8192];
    f32x4 acc[4][4] = {};
    mfma_core_128(probs + ((size_t)h * S + m0) * LT + kbeg, LT,
                  valsT + (size_t)h * D * LT + kbeg, LT, K, As, Bs, 0, 0, acc);
    const int tid = threadIdx.x, lane = tid & 63, wid = tid >> 6;
    const int wr = (wid >> 1) * 64, wc = (wid & 1) * 64;
    const int fr = lane & 15, kg = lane >> 4;
    u16* dst = attp + (size_t)c * S * HID;
#pragma unroll
    for (int i = 0; i < 4; ++i) {
        int r0 = m0 + wr + i * 16 + kg * 4;
#pragma unroll
        for (int j = 0; j < 4; ++j) {
            int cc = h * D + wc + j * 16 + fr;
#pragma unroll
            for (int r = 0; r < 4; ++r)
                dst[(size_t)(r0 + r) * HID + cc] = f2bf(acc[i][j][r]);
        }
    }
}

// ---------------- reduce PV partials + normalize by row sum (from tile partials) ----------------
__global__ void pv_reduce(const u16* __restrict__ attp, const float* __restrict__ rsumpart,
                          u16* __restrict__ attno, int S) {
    long i = (long)blockIdx.x * 256 + threadIdx.x;    // ushort4 units
    long base = i * 4;
    int s = (int)(base >> 11);                        // /HID
    int cc = (int)(base & 2047);
    int h = cc >> 7;
    int Klim = ((s >> 7) << 7) + 256;
    int n = (Klim + KCH - 1) / KCH;
    long stride4 = (long)S * HID / 4;
    size_t ridx = (size_t)h * S + s;
    int ntt = (s >> 7) + 2;
    const float* rp = rsumpart + ridx * 10;
    float tot = 0.f;
    for (int t = 0; t < ntt; ++t) tot += rp[t];
    ushort4 a = ((const ushort4*)attp)[i];
    float v0 = bf2f(a.x), v1 = bf2f(a.y), v2 = bf2f(a.z), v3 = bf2f(a.w);
    if (n > 1) {
        ushort4 b = ((const ushort4*)attp)[i + stride4];
        v0 += bf2f(b.x); v1 += bf2f(b.y); v2 += bf2f(b.z); v3 += bf2f(b.w);
    }
    if (n > 2) {
        ushort4 b = ((const ushort4*)attp)[i + 2 * stride4];
        v0 += bf2f(b.x); v1 += bf2f(b.y); v2 += bf2f(b.z); v3 += bf2f(b.w);
    }
    float inv = 1.0f / tot;
    ((ushort4*)attno)[i] = make_ushort4(f2bf(v0 * inv), f2bf(v1 * inv),
                                        f2bf(v2 * inv), f2bf(v3 * inv));
}

// ---------------- out projection split-K x4: bf16 A,B -> f32 partials ----------------
__global__ __launch_bounds__(256, 3) void gemm_out_split(
    const u16* __restrict__ A, const u16* __restrict__ B,
    float* __restrict__ outp, int S)
{
    __shared__ u16 As[8192], Bs[8192];
    int b = blockIdx.y * gridDim.x + blockIdx.x;
    int ntot = gridDim.x * gridDim.y;
    if ((ntot & 7) == 0) { int cpx = ntot >> 3; b = (b & 7) * cpx + (b >> 3); }
    const int m0 = (b / gridDim.x) * 128, n0 = (b % gridDim.x) * 128;
    const int z = blockIdx.z;
    f32x4 acc[4][4] = {};
    mfma_core_128(A + z * 512, HID, B + z * 512, HID, 512, As, Bs, m0, n0, acc);
    const int tid = threadIdx.x, lane = tid & 63, wid = tid >> 6;
    const int wr = (wid >> 1) * 64, wc = (wid & 1) * 64;
    const int fr = lane & 15, kg = lane >> 4;
    float* dst = outp + (size_t)z * S * HID;
#pragma unroll
    for (int i = 0; i < 4; ++i) {
        int r0 = m0 + wr + i * 16 + kg * 4;
#pragma unroll
        for (int j = 0; j < 4; ++j) {
            int c = n0 + wc + j * 16 + fr;
#pragma unroll
            for (int r = 0; r < 4; ++r)
                dst[(size_t)(r0 + r) * HID + c] = acc[i][j][r];
        }
    }
}

__global__ void out_reduce(const float* __restrict__ outp, float* __restrict__ out,
                           long n4) {   // float4 units
    long i = (long)blockIdx.x * 256 + threadIdx.x;
    float4 a = ((const float4*)outp)[i];
    float4 b = ((const float4*)outp)[i + n4];
    float4 c = ((const float4*)outp)[i + 2 * n4];
    float4 d = ((const float4*)outp)[i + 3 * n4];
    ((float4*)out)[i] = make_float4((a.x + b.x) + (c.x + d.x),
                                    (a.y + b.y) + (c.y + d.y),
                                    (a.z + b.z) + (c.z + d.z),
                                    (a.w + b.w) + (c.w + d.w));
}

// ---------------- fused f32 -> bf16 convert over 8 regions (Wvn deferred) ----------------
struct ConvJob {
    const float* src[8];
    u16* dst[8];
    long nchunk[8];
    float sc[8];
    int b0[8];
    int nb[8];
    int nt[8];     // nontemporal-load flag (single-touch source)
};

__device__ __forceinline__ void conv_region16(const float* __restrict__ s,
        u16* __restrict__ d, long nchunk, float sc, int relb, int nb, int ntf) {
    int tid = threadIdx.x;
    for (long c = relb; c < nchunk; c += nb) {
        const f32x4* p = (const f32x4*)s + c * 1024;
        f32x4 v0, v1, v2, v3;
        if (ntf) {
            v0 = __builtin_nontemporal_load(p + tid);
            v1 = __builtin_nontemporal_load(p + tid + 256);
            v2 = __builtin_nontemporal_load(p + tid + 512);
            v3 = __builtin_nontemporal_load(p + tid + 768);
        } else {
            v0 = p[tid]; v1 = p[tid + 256]; v2 = p[tid + 512]; v3 = p[tid + 768];
        }
        uint2* o = (uint2*)d + c * 1024;
        o[tid]       = make_uint2(pk2(v0.x, v0.y, sc), pk2(v0.z, v0.w, sc));
        o[tid + 256] = make_uint2(pk2(v1.x, v1.y, sc), pk2(v1.z, v1.w, sc));
        o[tid + 512] = make_uint2(pk2(v2.x, v2.y, sc), pk2(v2.z, v2.w, sc));
        o[tid + 768] = make_uint2(pk2(v3.x, v3.y, sc), pk2(v3.z, v3.w, sc));
    }
}

__global__ __launch_bounds__(256) void conv_all(ConvJob jb) {
    int b = blockIdx.x;
#define PICKR(r) conv_region16(jb.src[r], jb.dst[r], jb.nchunk[r], jb.sc[r], b - jb.b0[r], jb.nb[r], jb.nt[r])
    if      (b < jb.b0[1]) PICKR(0);
    else if (b < jb.b0[2]) PICKR(1);
    else if (b < jb.b0[3]) PICKR(2);
    else if (b < jb.b0[4]) PICKR(3);
    else if (b < jb.b0[5]) PICKR(4);
    else if (b < jb.b0[6]) PICKR(5);
    else if (b < jb.b0[7]) PICKR(6);
    else                   PICKR(7);
#undef PICKR
}

__global__ void pack_bias(const float* __restrict__ bq, const float* __restrict__ bk,
                          const float* __restrict__ bv, const float* __restrict__ bq2,
                          float* __restrict__ bp) {
    int i = blockIdx.x * 256 + threadIdx.x;
    if (i >= NQKV) return;
    float v;
    if (i < 2048)      v = bq[i] * SCALE;
    else if (i < 2560) v = bk[i - 2048];
    else if (i < 3072) v = bv[i - 2560];
    else               v = bq2[i - 3072] * SCALE;
    bp[i] = v;
}

// ---------------- RoPE: sincos hoisted per-d, reused across 5 heads per wave ----------------
__global__ __launch_bounds__(256) void rope_bf(u16* __restrict__ qkv,
                                               const int* __restrict__ pos, int S) {
    int s = blockIdx.x;
    float p = (float)pos[s];
    u16* row = qkv + (size_t)s * NQKV;
    int d = threadIdx.x & 63;
    int wg = threadIdx.x >> 6;
    float inv = exp2f(-(float)d * 0.31143075889568833f);   // 1e6^(-d/64)
    float sn, cs; sincosf(p * inv, &sn, &cs);
#pragma unroll
    for (int hh = 0; hh < 5; ++hh) {
        int head = wg * 5 + hh;     // 0..19: q heads 0..15, k heads 16..19
        u16* ptr = row + head * 128 + d;
        float x0 = bf2f(ptr[0]), x1 = bf2f(ptr[64]);
        ptr[0]  = f2bf(x0 * cs - x1 * sn);
        ptr[64] = f2bf(x1 * cs + x0 * sn);
    }
}

// ---------------- fused: stats_reduce + colsum of hs ----------------
__global__ void stats_and_colsum(const float* __restrict__ ps, const float* __restrict__ pss,
                                 float* __restrict__ mu, float* __restrict__ inv, int KB,
                                 const float* __restrict__ hs, float* __restrict__ part, int S) {
    int nb_stats = KB / 256;
    int b = blockIdx.x;
    int tid = threadIdx.x;
    if (b < nb_stats) {
        int i = b * 256 + tid;
        float s = 0.f, ss = 0.f;
#pragma unroll
        for (int c = 0; c < 16; ++c) { s += ps[(size_t)c * KB + i]; ss += pss[(size_t)c * KB + i]; }
        float m  = s * (1.0f / HID);
        float va = ss * (1.0f / HID) - m * m;
        mu[i] = m;
        inv[i] = rsqrtf(va + 1e-5f);
    } else {
        int b2 = b - nb_stats;
        int cx = b2 & 7, ry = b2 >> 3;
        int c = cx * 256 + tid;
        int rows_per = S / 16;
        int r0 = ry * rows_per;
        float a = 0.f;
        for (int r = r0; r < r0 + rows_per; ++r) a += hs[(size_t)r * HID + c];
        part[(size_t)ry * HID + c] = a;
    }
}

__global__ void reduce_part(const float* __restrict__ part, float* __restrict__ out,
                            int nchunk, int ncols) {
    int c = blockIdx.x * 256 + threadIdx.x;
    float a = 0.f;
    for (int i = 0; i < nchunk; ++i) a += part[(size_t)i * ncols + c];
    out[c] = a;
}
__global__ __launch_bounds__(256) void mv_rows(const float* __restrict__ W,
        const float* __restrict__ x, const float* __restrict__ b, float Sb,
        float* __restrict__ y) {
    int row = blockIdx.x * 4 + (threadIdx.x >> 6);
    int lane = threadIdx.x & 63;
    const float4* w4 = (const float4*)(W + (size_t)row * HID);
    const float4* x4 = (const float4*)x;
    float a = 0.f;
#pragma unroll
    for (int c = 0; c < 8; ++c) {
        float4 wv = w4[lane + c * 64], xv = x4[lane + c * 64];
        a += wv.x * xv.x + wv.y * xv.y + wv.z * xv.z + wv.w * xv.w;
    }
    a = wave_red_sum(a);
    if (lane == 0) y[row] = a + Sb * b[row];
}
__global__ void zpart_and_scalars(const float* __restrict__ W, const float* __restrict__ q2s,
                                  float* __restrict__ part, const float* __restrict__ bkn,
                                  float* __restrict__ outs) {
    int b = blockIdx.x;
    int tid = threadIdx.x;
    if (b < 128) {
        int cx = b & 7, ry = b >> 3;
        int e = cx * 256 + tid;
        int r0 = ry * (HID / 16);
        float a = 0.f;
        for (int j = r0; j < r0 + HID / 16; ++j) a += q2s[j] * W[(size_t)j * HID + e];
        part[(size_t)ry * HID + e] = a;
    } else {
        float s1 = 0.f, s2 = 0.f;
        for (int c = tid; c < HID; c += 256) { float v = q2s[c]; s1 += v; s2 += bkn[c] * v; }
        __shared__ float sb[4];
        s1 = block_red_sum(s1, sb);
        s2 = block_red_sum(s2, sb);
        if (tid == 0) { outs[0] = s1; outs[1] = s2; }
    }
}
__global__ __launch_bounds__(256) void kb_scores2(const float* __restrict__ ke,
        const float* __restrict__ z, const float* __restrict__ mu,
        const float* __restrict__ inv, const float* __restrict__ scal2,
        float* __restrict__ sc) {
    int row = blockIdx.x * 4 + (threadIdx.x >> 6);
    int lane = threadIdx.x & 63;
    const float4* x4 = (const float4*)(ke + (size_t)row * HID);
    const float4* z4 = (const float4*)z;
    float a = 0.f;
#pragma unroll
    for (int c = 0; c < 8; ++c) {
        float4 xv = x4[lane + c * 64], zv = z4[lane + c * 64];
        a += xv.x * zv.x + xv.y * zv.y + xv.z * zv.z + xv.w * zv.w;
    }
    a = wave_red_sum(a);
    if (lane == 0) sc[row] = SCALE * inv[row] * ((a + scal2[1]) - mu[row] * scal2[0]);
}

// ---------------- top-k: 2D-tiled partial ranks (jax tie semantics) ----------------
__global__ __launch_bounds__(256) void topk_rank_part(
    const float* __restrict__ sc, int* __restrict__ prank, int KB) {
    __shared__ float sj[256];
    int tid = threadIdx.x;
    int i = blockIdx.x * 256 + tid;
    int j0 = blockIdx.y * 256;
    sj[tid] = sc[j0 + tid];
    __syncthreads();
    float si = sc[i];
    int jrel = i - j0;
    int r = 0;
#pragma unroll 8
    for (int j = 0; j < 256; ++j) {
        float v = sj[j];
        r += (v > si) || (v == si && j < jrel);
    }
    prank[(size_t)blockIdx.y * KB + i] = r;
}
__global__ void topk_flags2(const int* __restrict__ prank, int* __restrict__ flg,
                            int nchunk, int KB) {
    int i = blockIdx.x * 256 + threadIdx.x;
    int r = 0;
    for (int c = 0; c < nchunk; ++c) r += prank[(size_t)c * KB + i];
    flg[i] = (r < TOPK) ? 1 : 0;
}
__global__ void compact_idx(const int* __restrict__ flg, int* __restrict__ idx, int KB) {
    int lane = threadIdx.x;
    int base = 0;
    for (int c = 0; c < KB; c += 64) {
        int f = flg[c + lane];
        unsigned long long m = __ballot(f != 0);
        if (f) idx[base + __popcll(m & ((1ull << lane) - 1ull))] = c + lane;
        base += (int)__popcll(m);
    }
}

// ---------------- gather+convert the 128 selected keme / vame rows ----------------
__global__ __launch_bounds__(256) void gather_sel(
    const float* __restrict__ keme, const float* __restrict__ vame,
    const int* __restrict__ idx, u16* __restrict__ ksel, u16* __restrict__ vsel) {
    int t = blockIdx.x;
    int g = idx[t];
    int tid = threadIdx.x;
    const float4* pk = (const float4*)(keme + (size_t)g * HID);
    const float4* pv = (const float4*)(vame + (size_t)g * HID);
    float4 a0 = pk[tid], a1 = pk[tid + 256];
    float4 b0 = pv[tid], b1 = pv[tid + 256];
    uint2* dk = (uint2*)(ksel + (size_t)t * HID);
    uint2* dv = (uint2*)(vsel + (size_t)t * HID);
    dk[tid]       = make_uint2(pk2(a0.x, a0.y, 1.f), pk2(a0.z, a0.w, 1.f));
    dk[tid + 256] = make_uint2(pk2(a1.x, a1.y, 1.f), pk2(a1.z, a1.w, 1.f));
    dv[tid]       = make_uint2(pk2(b0.x, b0.y, 1.f), pk2(b0.z, b0.w, 1.f));
    dv[tid + 256] = make_uint2(pk2(b1.x, b1.y, 1.f), pk2(b1.z, b1.w, 1.f));
}

// ---------------- build valsT[h][d][k] = concat(kbvsel, v)[k][h*D+d] ----------------
__global__ __launch_bounds__(256) void build_valsT(
    const u16* __restrict__ kbvsel, const u16* __restrict__ qkv,
    u16* __restrict__ valsT, int S)
{
    const int h = blockIdx.y, k0 = blockIdx.x * 64;
    const int LT = TOPK + S;
    __shared__ u16 t[64][136];
    int tid = threadIdx.x;
#pragma unroll
    for (int r = 0; r < 4; ++r) {
        int f = tid + r * 256;
        int kk = f >> 4, c8 = (f & 15) * 8;
        int kg = k0 + kk;
        const u16* src;
        if (kg < TOPK) src = kbvsel + (size_t)kg * HID + h * D + c8;
        else           src = qkv + (size_t)(kg - TOPK) * NQKV + 2560 + (h >> 2) * D + c8;
        *(uint4*)&t[kk][c8] = *(const uint4*)src;
    }
    __syncthreads();
    int d = tid >> 1, kh = (tid & 1) * 32;
    u16* dst = valsT + ((size_t)h * D + d) * LT + k0 + kh;
#pragma unroll
    for (int i = 0; i < 8; ++i) {
        ushort4 o = make_ushort4(t[kh + i*4 + 0][d], t[kh + i*4 + 1][d],
                                 t[kh + i*4 + 2][d], t[kh + i*4 + 3][d]);
        *(ushort4*)(dst + i * 4) = o;
    }
}

extern "C" void kernel_launch(void* const* d_in, const int* in_sizes, int n_in,
                              void* d_out, int out_size, void* d_ws, size_t ws_size,
                              hipStream_t stream) {
    const float* hs   = (const float*)d_in[0];
    const float* keme = (const float*)d_in[1];
    const float* vame = (const float*)d_in[2];
    const int*   pos  = (const int*)d_in[3];
    const float* Wq   = (const float*)d_in[4];
    const float* bq   = (const float*)d_in[5];
    const float* Wk   = (const float*)d_in[6];
    const float* bk_  = (const float*)d_in[7];
    const float* Wv   = (const float*)d_in[8];
    const float* bv   = (const float*)d_in[9];
    const float* Wq2  = (const float*)d_in[10];
    const float* bq2  = (const float*)d_in[11];
    const float* Wkn  = (const float*)d_in[12];
    const float* bkn  = (const float*)d_in[13];
    const float* Wvn  = (const float*)d_in[14];
    const float* bvn  = (const float*)d_in[15];
    const float* Wo   = (const float*)d_in[16];
    float* out = (float*)d_out;

    const int S  = in_sizes[3];
    const int KB = in_sizes[1] / HID;
    const int LT = TOPK + S;
    const int NS = S / 128;

    char* w = (char*)d_ws;
    auto carve = [&](size_t bytes) { char* p = w; w += (bytes + 255) & ~(size_t)255; return p; };
    u16* hsbf   = (u16*)carve((size_t)S * HID * 2);
    u16* kebf   = (u16*)carve((size_t)KB * HID * 2);
    u16* wpack  = (u16*)carve((size_t)NQKV * HID * 2);
    u16* wknbf  = (u16*)carve((size_t)HID * HID * 2);
    u16* wvnbf  = (u16*)carve((size_t)HID * HID * 2);
    u16* wobf   = (u16*)carve((size_t)HID * HID * 2);
    float* bpk  = (float*)carve(NQKV * 4);
    u16* qkv    = (u16*)carve((size_t)S * NQKV * 2);
    float* mu   = (float*)carve((size_t)KB * 4);
    float* inv  = (float*)carve((size_t)KB * 4);
    float* part_s  = (float*)carve((size_t)16 * KB * 4);
    float* part_ss = (float*)carve((size_t)16 * KB * 4);
    u16* probs  = (u16*)carve((size_t)H * S * LT * 2);
    u16* valsT  = (u16*)carve((size_t)H * D * LT * 2);
    u16* attp   = (u16*)carve((size_t)3 * S * HID * 2);
    u16* attno  = (u16*)carve((size_t)S * HID * 2);
    float* outp = (float*)carve((size_t)4 * S * HID * 4);
    float* rsumpart = (float*)carve((size_t)H * S * 10 * 4);
    u16* ksel   = (u16*)carve((size_t)TOPK * HID * 2);
    u16* vsel   = (u16*)carve((size_t)TOPK * HID * 2);
    u16* kbksel = (u16*)carve((size_t)TOPK * HID * 2);
    u16* kbvsel = (u16*)carve((size_t)TOPK * HID * 2);
    float* hsum = (float*)carve(HID * 4);
    float* q2s  = (float*)carve(HID * 4);
    float* zv   = (float*)carve(HID * 4);
    float* part = (float*)carve((size_t)16 * HID * 4);
    float* scal2= (float*)carve(2 * 4);
    float* sc   = (float*)carve((size_t)KB * 4);
    int* prank  = (int*)carve((size_t)(KB / 256) * KB * 4);
    int* flg    = (int*)carve((size_t)KB * 4);
    int* idx    = (int*)carve(TOPK * 4);

    // ---- fused convert dispatch: 8 regions (Wvn deferred into proj dispatch) ----
    ConvJob jb;
    const float* srcs[8] = {hs, keme, Wq, Wk, Wv, Wq2, Wkn, Wo};
    u16* dsts[8] = {hsbf, kebf, wpack, wpack + (size_t)2048 * HID,
                    wpack + (size_t)2560 * HID, wpack + (size_t)3072 * HID,
                    wknbf, wobf};
    long nel[8] = {(long)S * HID, (long)KB * HID,
                   (long)HID * HID, (long)512 * HID, (long)512 * HID,
                   (long)HID * HID, (long)HID * HID, (long)HID * HID};
    float scls[8] = {1.f, 1.f, SCALE, 1.f, 1.f, SCALE, 1.f, 1.f};
    int ntfs[8] = {0, 0, 1, 1, 1, 0, 0, 1};
    long totc = 0;
    for (int r = 0; r < 8; ++r) totc += nel[r] / 4096;
    int btot = 0;
    for (int r = 0; r < 8; ++r) {
        long nch = nel[r] / 4096;
        int nb = (int)((2048.0 * (double)nch) / (double)totc + 0.5);
        if (nb < 1) nb = 1;
        jb.src[r] = srcs[r]; jb.dst[r] = dsts[r]; jb.nchunk[r] = nch;
        jb.sc[r] = scls[r]; jb.b0[r] = btot; jb.nb[r] = nb; jb.nt[r] = ntfs[r];
        btot += nb;
    }
    conv_all<<<btot, 256, 0, stream>>>(jb);
    pack_bias<<<NQKV / 256, 256, 0, stream>>>(bq, bk_, bv, bq2, bpk);

    // ---- merged projections (QKV + KB-stats) + appended Wvn conversion ----
    int nproj = (NQKV / 128) * (S / 128) + (HID / 128) * (KB / 128);
    gemm_proj_all<<<nproj + 256, 256, 0, stream>>>(
        hsbf, wpack, bpk, qkv, kebf, wknbf, bkn, part_s, part_ss, S, KB,
        Wvn, wvnbf);

    rope_bf<<<S, 256, 0, stream>>>(qkv, pos, S);
    stats_and_colsum<<<KB / 256 + 128, 256, 0, stream>>>(
        part_s, part_ss, mu, inv, KB, hs, part, S);
    reduce_part<<<HID / 256, 256, 0, stream>>>(part, hsum, 16, HID);
    mv_rows<<<HID / 4, 256, 0, stream>>>(Wq2, hsum, bq2, (float)S, q2s);
    zpart_and_scalars<<<129, 256, 0, stream>>>(Wkn, q2s, part, bkn, scal2);
    reduce_part<<<HID / 256, 256, 0, stream>>>(part, zv, 16, HID);
    kb_scores2<<<KB / 4, 256, 0, stream>>>(keme, zv, mu, inv, scal2, sc);

    // ---- top-k + ascending compaction ----
    topk_rank_part<<<dim3(KB / 256, KB / 256), 256, 0, stream>>>(sc, prank, KB);
    topk_flags2<<<KB / 256, 256, 0, stream>>>(prank, flg, KB / 256, KB);
    compact_idx<<<1, 64, 0, stream>>>(flg, idx, KB);

    // ---- selected rows: gather+convert, pair GEMM (kbk w/ LN, kbv) ----
    gather_sel<<<TOPK, 256, 0, stream>>>(keme, vame, idx, ksel, vsel);
    gemm_sel_pair<<<dim3(HID / 128, 1, 2), 256, 0, stream>>>(
        ksel, vsel, wknbf, wvnbf, bkn, bvn, mu, inv, idx, kbksel, kbvsel);

    build_valsT<<<dim3(LT / 64, H), 256, 0, stream>>>(kbvsel, qkv, valsT, S);

    // ---- logits -> unnormalized probs (fixed-reference exp) + row-sum partials ----
    logits_all<<<dim3(NS * (NS + 1) / 2 + NS, H), 256, 0, stream>>>(
        qkv, kbksel, probs, rsumpart, S);

    // ---- PV (plain GEMM, K-split x3) + reduce/normalize ----
    pv_split<<<dim3(S / 128, H, 3), 256, 0, stream>>>(probs, valsT, attp, S);
    pv_reduce<<<(int)((size_t)S * HID / 1024), 256, 0, stream>>>(
        attp, rsumpart, attno, S);

    // ---- output projection (split-K x4 + reduce) ----
    gemm_out_split<<<dim3(HID / 128, S / 128, 4), 256, 0, stream>>>(
        attno, wobf, outp, S);
    out_reduce<<<(int)((size_t)S * HID / 1024), 256, 0, stream>>>(
        outp, out, (long)S * HID / 4);
}